// Round 22
// baseline (162.539 us; speedup 1.0000x reference)
//
#include <hip/hip_runtime.h>
#include <hip/hip_bf16.h>

#define DIM 256
#define NHEADS 4
#define HDIM 64
#define NPIX 2304          // 48*48
#define NBATCH 8
#define KCN 72             // NPIX/32 key chunks
#define NTN 144            // NPIX/16 n-tiles (fragment-order X/Op)
#define SCALE_L2E 0.18033688011112042f   // 0.125 * log2(e), folded into Q
#define CLAMP_L2E 8.656170245332781f     // 6.0  * log2(e)

typedef __hip_bfloat16 bf16;
typedef __bf16 bf16x8 __attribute__((ext_vector_type(8)));
typedef float  f32x4  __attribute__((ext_vector_type(4)));
typedef float  f32x16 __attribute__((ext_vector_type(16)));

__device__ __forceinline__ unsigned int pack2bf(float a, float b) {
    __hip_bfloat162 h = __float22bfloat162_rn(float2{a, b});
    union { __hip_bfloat162 h; unsigned int u; } c; c.h = h;
    return c.u;
}

// ---- 4 weight mats (256x256 f32 row-major (m,c)) -> fragment-order bf16:
// FW[mh][kc][mt][lane=hi*16+lo][j], m = mh*128+mt*16+lo, c = kc*32+hi*8+j.
__global__ __launch_bounds__(256) void cvt_w_kernel(
    const float* __restrict__ w0, const float* __restrict__ w1,
    const float* __restrict__ w2, const float* __restrict__ w3,
    bf16* __restrict__ out)
{
    const int sel = blockIdx.y;
    const float* src = sel == 0 ? w0 : sel == 1 ? w1 : sel == 2 ? w2 : w3;
    const int i = blockIdx.x * 256 + threadIdx.x;   // 8 elems per thread
    const int m = i >> 5, c0 = (i & 31) * 8;
    const int mh = m >> 7, mt = (m >> 4) & 7, lo = m & 15;
    const int kc = c0 >> 5, hi = (c0 >> 3) & 3;
    float4 a = *(const float4*)(src + i * 8);
    float4 b = *(const float4*)(src + i * 8 + 4);
    uint4 u;
    u.x = pack2bf(a.x, a.y); u.y = pack2bf(a.z, a.w);
    u.z = pack2bf(b.x, b.y); u.w = pack2bf(b.z, b.w);
    const size_t fb = (((size_t)(mh * 8 + kc)) * 8 + mt) * 512 + (hi * 16 + lo) * 8;
    *(uint4*)(void*)(out + (size_t)sel * 65536 + fb) = u;
}

// ---- src/tgt (b,c,n) f32 -> fragment-order bf16 FX[b][ntile][kc][lane][j]
// (n = ntile*16 + lo, c = kc*32 + hi*8 + j) via LDS tile transpose.
__global__ __launch_bounds__(256) void txp_kernel(
    const float* __restrict__ src, const float* __restrict__ tgt,
    bf16* __restrict__ oS, bf16* __restrict__ oT)
{
    const int b = blockIdx.z & 7;
    const float* in = (blockIdx.z >> 3) ? tgt : src;
    bf16* out = (blockIdx.z >> 3) ? oT : oS;
    const int n0 = blockIdx.x * 64, c0 = blockIdx.y * 64;
    __shared__ float tile[64][65];
    const int t = threadIdx.x;
#pragma unroll
    for (int i = 0; i < 4; ++i) {
        int idx = t + i * 256;
        int cl = idx >> 4, n4 = (idx & 15) * 4;
        float4 v = *(const float4*)(in + ((size_t)b * DIM + c0 + cl) * NPIX + n0 + n4);
        tile[cl][n4] = v.x; tile[cl][n4 + 1] = v.y;
        tile[cl][n4 + 2] = v.z; tile[cl][n4 + 3] = v.w;
    }
    __syncthreads();
#pragma unroll
    for (int i = 0; i < 2; ++i) {
        int idx = t + i * 256;
        int nl = idx >> 3, c8 = (idx & 7) * 8;
        uint4 u;
        u.x = pack2bf(tile[c8 + 0][nl], tile[c8 + 1][nl]);
        u.y = pack2bf(tile[c8 + 2][nl], tile[c8 + 3][nl]);
        u.z = pack2bf(tile[c8 + 4][nl], tile[c8 + 5][nl]);
        u.w = pack2bf(tile[c8 + 6][nl], tile[c8 + 7][nl]);
        const int n = n0 + nl, c = c0 + c8;
        const size_t fb = (((size_t)(b * NTN + (n >> 4))) * 8 + (c >> 5)) * 512
                        + ((((c >> 3) & 3) * 16) + (n & 15)) * 8;
        *(uint4*)(void*)(out + fb) = u;
    }
}

// ---- 1x1 conv, all operands fragment-order (lane-linear 16B loads), K-SPLIT:
// block = 32n x 128m, 4 waves = (wn, wk); wave: 16n x 128m x K128 (4 kc),
// exact f32 LDS reduce across wk. Grid (72, 2, 8).
// X: FX[b][ntile][kc][lane][j]; W: FW[mh][kc][mt][lane][j].
// MODE 0: f32 (b,c,n) -> Yf. MODE 1: *scale -> QF/KF frag-order (attn).
// MODE 2: -> VF frag-order (attn).
template <int MODE>
__global__ __launch_bounds__(256, 3) void conv_kernel(
    const bf16* __restrict__ X, const bf16* __restrict__ Wb,
    const float* __restrict__ bias, float scale,
    bf16* __restrict__ Yb, float* __restrict__ Yf)
{
    const int b  = blockIdx.z, mh = blockIdx.y;
    const int n0 = blockIdx.x * 32;
    const int w  = threadIdx.x >> 6, l = threadIdx.x & 63;
    const int wn = w & 1, wk = w >> 1;
    const int lo = l & 15, hi = l >> 4;

    __shared__ float red[2][64][36];   // [wn][lane][32 acc] (pad 36: f4-aligned)

    const int ntile = blockIdx.x * 2 + wn;
    const bf16* xp = X + ((size_t)(b * NTN + ntile) * 8) * 512 + l * 8;
    const bf16* wp = Wb + (size_t)mh * 32768 + l * 8;

    f32x4 acc[8];
#pragma unroll
    for (int mt = 0; mt < 8; ++mt) acc[mt] = (f32x4){0.f, 0.f, 0.f, 0.f};

    const int kbase = wk * 4;
    bf16x8 a = *(const bf16x8*)(const void*)(xp + (size_t)kbase * 512);
    bf16x8 bfr[8];
#pragma unroll
    for (int mt = 0; mt < 8; ++mt)
        bfr[mt] = *(const bf16x8*)(const void*)(wp + (size_t)(kbase * 8 + mt) * 512);

#pragma unroll
    for (int ki = 0; ki < 4; ++ki) {
        const int kn = kbase + ((ki + 1) & 3);   // wrap: harmless L1-hit reload
        bf16x8 a2 = *(const bf16x8*)(const void*)(xp + (size_t)kn * 512);
        bf16x8 bfr2[8];
#pragma unroll
        for (int mt = 0; mt < 8; ++mt)
            bfr2[mt] = *(const bf16x8*)(const void*)(wp + (size_t)(kn * 8 + mt) * 512);
#pragma unroll
        for (int mt = 0; mt < 8; ++mt)
            acc[mt] = __builtin_amdgcn_mfma_f32_16x16x32_bf16(a, bfr[mt], acc[mt], 0, 0, 0);
        a = a2;
#pragma unroll
        for (int mt = 0; mt < 8; ++mt) bfr[mt] = bfr2[mt];
    }

    // ---- exact cross-wave K-reduction ----
    if (wk == 1) {
#pragma unroll
        for (int mt = 0; mt < 8; ++mt)
            *(float4*)&red[wn][l][mt * 4] = make_float4(acc[mt][0], acc[mt][1],
                                                        acc[mt][2], acc[mt][3]);
    }
    __syncthreads();
    if (wk != 0) return;

#pragma unroll
    for (int mt = 0; mt < 8; ++mt) {
        float4 v = *(float4*)&red[wn][l][mt * 4];
        acc[mt][0] += v.x; acc[mt][1] += v.y; acc[mt][2] += v.z; acc[mt][3] += v.w;
    }

    const int nb = n0 + wn * 16 + hi * 4;   // first of 4 consecutive n (rows r)
#pragma unroll
    for (int mt = 0; mt < 8; ++mt) {
        const int m = mh * 128 + mt * 16 + lo;
        const float bv = bias[m];
        if (MODE == 1) {
            const int h = m >> 6, d = m & 63;
            const size_t fb = (((size_t)(b * NHEADS + h) * KCN + (nb >> 5)) * 4 + (d >> 4)) * 512
                            + ((((d >> 3) & 1) * 32) + (nb & 31)) * 8 + (d & 7);
#pragma unroll
            for (int r = 0; r < 4; ++r)
                Yb[fb + r * 8] = __float2bfloat16((acc[mt][r] + bv) * scale);
        } else if (MODE == 2) {
            const int h = m >> 6, dv = m & 63;
            const size_t fb = ((((size_t)(b * NHEADS + h) * KCN + (nb >> 5)) * 2 + ((nb >> 4) & 1)) * 2
                               + (dv >> 5)) * 512
                            + ((((nb >> 3) & 1) * 32) + (dv & 31)) * 8 + (nb & 7);
            uint2 u = make_uint2(pack2bf(acc[mt][0] + bv, acc[mt][1] + bv),
                                 pack2bf(acc[mt][2] + bv, acc[mt][3] + bv));
            *(uint2*)(void*)(Yb + fb) = u;
        } else {
            float4 v = make_float4(acc[mt][0] + bv, acc[mt][1] + bv,
                                   acc[mt][2] + bv, acc[mt][3] + bv);
            *(float4*)(void*)(Yf + ((size_t)b * DIM + m) * NPIX + nb) = v;
        }
    }
}

// ---- MFMA flash attention: 512-thread block = TWO independent R19-style
// virtual blocks (vb = w>>2), each 4 waves (wq = w&1, wk = (w>>1)&1) with the
// VERIFIED R19 schedule: wq owns a 32-q subtile of q-tile (bx*2+vb); wk owns
// 36 chunks kc = wk + 2i; single-barrier 2-way reduction. Disjoint shared
// buffers per vb. Forces 8-wave co-residency (R20's occupancy goal) with
// only R19-verified control flow. Grid (18,4,8), block 512.
__global__ __launch_bounds__(512, 2) void attn_kernel(
    const bf16* __restrict__ Qt, const bf16* __restrict__ Kt,
    const bf16* __restrict__ Vt, bf16* __restrict__ Op)
{
    const int b = blockIdx.z, h = blockIdx.y;
    const int w = threadIdx.x >> 6;
    const int vb = w >> 2;                    // virtual block 0/1
    const int wq = w & 1, wk = (w >> 1) & 1;  // R19 roles within virtual block
    const int l = threadIdx.x & 63;
    const int ln = l & 31, h2 = l >> 5;
    const int bh = b * NHEADS + h;
    const int qt = blockIdx.x * 2 + vb;       // 64-query tile index (0..35)

    __shared__ float red[2][2][32][68];       // [vb][wq][q][d]
    __shared__ float lred[2][2][32];          // [vb][wq][q]

    const bf16* QB = Qt + ((size_t)bh * KCN + qt * 2 + wq) * 2048 + l * 8;
    const bf16* KB = Kt + (size_t)bh * KCN * 2048 + l * 8;
    const bf16* VB = Vt + (size_t)bh * KCN * 2048 + l * 8;

    // Q B-frags: lane holds Q[q = qt*64 + wq*32 + ln][dk*16+h2*8+j]
    bf16x8 qf[4];
#pragma unroll
    for (int dk = 0; dk < 4; ++dk)
        qf[dk] = *(const bf16x8*)(const void*)(QB + dk * 512);

    f32x16 oacc[2];   // [dt]: O^T[d = dt*32 + row][q]
#pragma unroll
    for (int dt = 0; dt < 2; ++dt)
#pragma unroll
        for (int r = 0; r < 16; ++r) oacc[dt][r] = 0.f;
    float lsum = 0.f;

    bf16x8 kfA[4], kfB[4];
    bf16x8 vfA[2][2], vfB[2][2];

    auto load_chunk = [&](int kc_, bf16x8 (&kfD)[4], bf16x8 (&vfD)[2][2]) {
        const bf16* KBn = KB + (size_t)kc_ * 2048;
        const bf16* VBn = VB + (size_t)kc_ * 2048;
#pragma unroll
        for (int dk = 0; dk < 4; ++dk)
            kfD[dk] = *(const bf16x8*)(const void*)(KBn + dk * 512);
#pragma unroll
        for (int kb = 0; kb < 2; ++kb)
#pragma unroll
            for (int dt = 0; dt < 2; ++dt)
                vfD[kb][dt] = *(const bf16x8*)(const void*)(VBn + kb * 1024 + dt * 512);
    };

    auto compute = [&](const bf16x8 (&kfX)[4], const bf16x8 (&vfX)[2][2]) {
        f32x16 s;
#pragma unroll
        for (int r = 0; r < 16; ++r) s[r] = 0.f;
#pragma unroll
        for (int dk = 0; dk < 4; ++dk)
            s = __builtin_amdgcn_mfma_f32_32x32x16_bf16(kfX[dk], qf[dk], s, 0, 0, 0);

        // P = exp2(clamp(S)); word p covers keys 8*(p>>1)+4*h2+2*(p&1)+{0,1}
        float ls = 0.f;
        unsigned int pk[8];
#pragma unroll
        for (int p = 0; p < 8; ++p) {
            float ea = __builtin_amdgcn_exp2f(
                __builtin_amdgcn_fmed3f(s[2 * p],     -CLAMP_L2E, CLAMP_L2E));
            float eb = __builtin_amdgcn_exp2f(
                __builtin_amdgcn_fmed3f(s[2 * p + 1], -CLAMP_L2E, CLAMP_L2E));
            ls += ea + eb;
            pk[p] = pack2bf(ea, eb);
        }
        lsum += ls;

        // P^T B-frags via half-wave swaps:
        // after swap(a,b): a = {a.lo32 | b.lo32}, b = {a.hi32 | b.hi32}
        unsigned int c00 = pk[0], c02 = pk[2], c01 = pk[1], c03 = pk[3];
        unsigned int c10 = pk[4], c12 = pk[6], c11 = pk[5], c13 = pk[7];
        asm("v_permlane32_swap_b32 %0, %1" : "+v"(c00), "+v"(c02));
        asm("v_permlane32_swap_b32 %0, %1" : "+v"(c01), "+v"(c03));
        asm("v_permlane32_swap_b32 %0, %1" : "+v"(c10), "+v"(c12));
        asm("v_permlane32_swap_b32 %0, %1" : "+v"(c11), "+v"(c13));
        union { unsigned int u[4]; bf16x8 v; } pb0, pb1;
        pb0.u[0] = c00; pb0.u[1] = c01; pb0.u[2] = c02; pb0.u[3] = c03;
        pb1.u[0] = c10; pb1.u[1] = c11; pb1.u[2] = c12; pb1.u[3] = c13;

#pragma unroll
        for (int dt = 0; dt < 2; ++dt) {
            oacc[dt] = __builtin_amdgcn_mfma_f32_32x32x16_bf16(vfX[0][dt], pb0.v, oacc[dt], 0, 0, 0);
            oacc[dt] = __builtin_amdgcn_mfma_f32_32x32x16_bf16(vfX[1][dt], pb1.v, oacc[dt], 0, 0, 0);
        }
    };

    // wave (vb,wq,wk): 36 chunks kc = wk + 2i (R19 schedule), ping-pong prefetched
    load_chunk(wk, kfA, vfA);
    for (int i = 0; i < 36; i += 2) {
        load_chunk(wk + 2 * (i + 1), kfB, vfB);
        compute(kfA, vfA);
        load_chunk(i + 2 < 36 ? wk + 2 * (i + 2) : wk, kfA, vfA);  // wrap: harmless reload
        compute(kfB, vfB);
    }

    // ---- 2-way exact cross-wave reduction per (vb, wq) — R19 structure ----
    lsum += __shfl_xor(lsum, 32);
    if (wk == 1) {
        if (h2 == 0) lred[vb][wq][ln] = lsum;
#pragma unroll
        for (int dt = 0; dt < 2; ++dt)
#pragma unroll
            for (int g = 0; g < 4; ++g) {
                float4 v = make_float4(oacc[dt][g * 4 + 0], oacc[dt][g * 4 + 1],
                                       oacc[dt][g * 4 + 2], oacc[dt][g * 4 + 3]);
                *(float4*)&red[vb][wq][ln][dt * 32 + g * 8 + h2 * 4] = v;
            }
    }
    __syncthreads();

    if (wk == 0) {
#pragma unroll
        for (int dt = 0; dt < 2; ++dt)
#pragma unroll
            for (int g = 0; g < 4; ++g) {
                float4 v = *(float4*)&red[vb][wq][ln][dt * 32 + g * 8 + h2 * 4];
                oacc[dt][g * 4 + 0] += v.x; oacc[dt][g * 4 + 1] += v.y;
                oacc[dt][g * 4 + 2] += v.z; oacc[dt][g * 4 + 3] += v.w;
            }
        const float inv = 1.f / (lsum + lred[vb][wq][ln]);

        // store FOp fragment-order: elem (n = qt*64+wq*32+ln, c = h*64+dt*32+g*8+h2*4+e)
        const int ntile = qt * 4 + wq * 2 + (ln >> 4);
        bf16* opb = Op + (((size_t)(b * NTN + ntile)) * 8 + h * 2) * 512
                  + (ln & 15) * 8 + h2 * 4;
#pragma unroll
        for (int dt = 0; dt < 2; ++dt)
#pragma unroll
            for (int g = 0; g < 4; ++g) {
                float v0 = oacc[dt][g * 4 + 0] * inv;
                float v1 = oacc[dt][g * 4 + 1] * inv;
                float v2 = oacc[dt][g * 4 + 2] * inv;
                float v3 = oacc[dt][g * 4 + 3] * inv;
                uint2 u = make_uint2(pack2bf(v0, v1), pack2bf(v2, v3));
                *(uint2*)(void*)(opb + (size_t)dt * 512 + g * 128) = u;
            }
    }
}

extern "C" void kernel_launch(void* const* d_in, const int* in_sizes, int n_in,
                              void* d_out, int out_size, void* d_ws, size_t ws_size,
                              hipStream_t stream) {
    const float* src = (const float*)d_in[0];
    const float* tgt = (const float*)d_in[1];
    const float* qw  = (const float*)d_in[2];
    const float* qb  = (const float*)d_in[3];
    const float* kw  = (const float*)d_in[4];
    const float* kb  = (const float*)d_in[5];
    const float* vw  = (const float*)d_in[6];
    const float* vb  = (const float*)d_in[7];
    const float* ow  = (const float*)d_in[8];
    const float* ob  = (const float*)d_in[9];
    float* out = (float*)d_out;

    const size_t TEN = (size_t)NBATCH * DIM * NPIX;  // 4,718,592
    bf16* Wbf  = (bf16*)d_ws;          // 4 x 65536, fragment-order
    bf16* XbfS = Wbf  + 4 * 65536;     // FX[b][ntile][kc][lane][j]
    bf16* XbfT = XbfS + TEN;
    bf16* Qt   = XbfT + TEN;           // fragment-order QF, prescaled
    bf16* Kt   = Qt   + TEN;           // fragment-order KF
    bf16* Vt   = Kt   + TEN;           // fragment-order VF
    bf16* Op   = Vt   + TEN;           // fragment-order FOp

    cvt_w_kernel<<<dim3(32, 4, 1), 256, 0, stream>>>(qw, kw, vw, ow, Wbf);
    txp_kernel<<<dim3(NPIX / 64, DIM / 64, 2 * NBATCH), 256, 0, stream>>>(src, tgt, XbfS, XbfT);

    dim3 cgrid(NPIX / 32, 2, NBATCH);
    conv_kernel<1><<<cgrid, 256, 0, stream>>>(XbfS, Wbf,             qb, SCALE_L2E, Qt, nullptr);
    conv_kernel<1><<<cgrid, 256, 0, stream>>>(XbfT, Wbf + 1 * 65536, kb, 1.0f,      Kt, nullptr);
    conv_kernel<2><<<cgrid, 256, 0, stream>>>(XbfT, Wbf + 2 * 65536, vb, 1.0f,      Vt, nullptr);

    attn_kernel<<<dim3(NPIX / 128, NHEADS, NBATCH), 512, 0, stream>>>(Qt, Kt, Vt, Op);

    conv_kernel<0><<<cgrid, 256, 0, stream>>>(Op, Wbf + 3 * 65536, ob, 1.0f, nullptr, out);
}

// Round 23
// 131.603 us; speedup vs baseline: 1.2351x; 1.2351x over previous
//
#include <hip/hip_runtime.h>
#include <hip/hip_bf16.h>

#define DIM 256
#define NHEADS 4
#define HDIM 64
#define NPIX 2304          // 48*48
#define NBATCH 8
#define KCN 72             // NPIX/32 key chunks
#define NTN 144            // NPIX/16 n-tiles (fragment-order X/Op)
#define SCALE_L2E 0.18033688011112042f   // 0.125 * log2(e), folded into Q
#define CLAMP_L2E 8.656170245332781f     // 6.0  * log2(e)

typedef __hip_bfloat16 bf16;
typedef __bf16 bf16x8 __attribute__((ext_vector_type(8)));
typedef float  f32x4  __attribute__((ext_vector_type(4)));
typedef float  f32x16 __attribute__((ext_vector_type(16)));

__device__ __forceinline__ unsigned int pack2bf(float a, float b) {
    __hip_bfloat162 h = __float22bfloat162_rn(float2{a, b});
    union { __hip_bfloat162 h; unsigned int u; } c; c.h = h;
    return c.u;
}

// ---- 4 weight mats (256x256 f32 row-major (m,c)) -> fragment-order bf16:
// FW[mh][kc][mt][lane=hi*16+lo][j], m = mh*128+mt*16+lo, c = kc*32+hi*8+j.
__global__ __launch_bounds__(256) void cvt_w_kernel(
    const float* __restrict__ w0, const float* __restrict__ w1,
    const float* __restrict__ w2, const float* __restrict__ w3,
    bf16* __restrict__ out)
{
    const int sel = blockIdx.y;
    const float* src = sel == 0 ? w0 : sel == 1 ? w1 : sel == 2 ? w2 : w3;
    const int i = blockIdx.x * 256 + threadIdx.x;   // 8 elems per thread
    const int m = i >> 5, c0 = (i & 31) * 8;
    const int mh = m >> 7, mt = (m >> 4) & 7, lo = m & 15;
    const int kc = c0 >> 5, hi = (c0 >> 3) & 3;
    float4 a = *(const float4*)(src + i * 8);
    float4 b = *(const float4*)(src + i * 8 + 4);
    uint4 u;
    u.x = pack2bf(a.x, a.y); u.y = pack2bf(a.z, a.w);
    u.z = pack2bf(b.x, b.y); u.w = pack2bf(b.z, b.w);
    const size_t fb = (((size_t)(mh * 8 + kc)) * 8 + mt) * 512 + (hi * 16 + lo) * 8;
    *(uint4*)(void*)(out + (size_t)sel * 65536 + fb) = u;
}

// ---- src/tgt (b,c,n) f32 -> fragment-order bf16 FX[b][ntile][kc][lane][j]
// (n = ntile*16 + lo, c = kc*32 + hi*8 + j) via LDS tile transpose.
__global__ __launch_bounds__(256) void txp_kernel(
    const float* __restrict__ src, const float* __restrict__ tgt,
    bf16* __restrict__ oS, bf16* __restrict__ oT)
{
    const int b = blockIdx.z & 7;
    const float* in = (blockIdx.z >> 3) ? tgt : src;
    bf16* out = (blockIdx.z >> 3) ? oT : oS;
    const int n0 = blockIdx.x * 64, c0 = blockIdx.y * 64;
    __shared__ float tile[64][65];
    const int t = threadIdx.x;
#pragma unroll
    for (int i = 0; i < 4; ++i) {
        int idx = t + i * 256;
        int cl = idx >> 4, n4 = (idx & 15) * 4;
        float4 v = *(const float4*)(in + ((size_t)b * DIM + c0 + cl) * NPIX + n0 + n4);
        tile[cl][n4] = v.x; tile[cl][n4 + 1] = v.y;
        tile[cl][n4 + 2] = v.z; tile[cl][n4 + 3] = v.w;
    }
    __syncthreads();
#pragma unroll
    for (int i = 0; i < 2; ++i) {
        int idx = t + i * 256;
        int nl = idx >> 3, c8 = (idx & 7) * 8;
        uint4 u;
        u.x = pack2bf(tile[c8 + 0][nl], tile[c8 + 1][nl]);
        u.y = pack2bf(tile[c8 + 2][nl], tile[c8 + 3][nl]);
        u.z = pack2bf(tile[c8 + 4][nl], tile[c8 + 5][nl]);
        u.w = pack2bf(tile[c8 + 6][nl], tile[c8 + 7][nl]);
        const int n = n0 + nl, c = c0 + c8;
        const size_t fb = (((size_t)(b * NTN + (n >> 4))) * 8 + (c >> 5)) * 512
                        + ((((c >> 3) & 3) * 16) + (n & 15)) * 8;
        *(uint4*)(void*)(out + fb) = u;
    }
}

// ---- shared conv core: 32n x 128m, 4 waves (wn, wk), K-split + LDS reduce.
// Returns via acc; caller does epilogue. X/W fragment-order (lane-linear 16B).
__device__ __forceinline__ void conv_core(
    const bf16* __restrict__ xp, const bf16* __restrict__ wp,
    int wk, f32x4 (&acc)[8])
{
#pragma unroll
    for (int mt = 0; mt < 8; ++mt) acc[mt] = (f32x4){0.f, 0.f, 0.f, 0.f};

    const int kbase = wk * 4;
    bf16x8 a = *(const bf16x8*)(const void*)(xp + (size_t)kbase * 512);
    bf16x8 bfr[8];
#pragma unroll
    for (int mt = 0; mt < 8; ++mt)
        bfr[mt] = *(const bf16x8*)(const void*)(wp + (size_t)(kbase * 8 + mt) * 512);

#pragma unroll
    for (int ki = 0; ki < 4; ++ki) {
        const int kn = kbase + ((ki + 1) & 3);   // wrap: harmless L1-hit reload
        bf16x8 a2 = *(const bf16x8*)(const void*)(xp + (size_t)kn * 512);
        bf16x8 bfr2[8];
#pragma unroll
        for (int mt = 0; mt < 8; ++mt)
            bfr2[mt] = *(const bf16x8*)(const void*)(wp + (size_t)(kn * 8 + mt) * 512);
#pragma unroll
        for (int mt = 0; mt < 8; ++mt)
            acc[mt] = __builtin_amdgcn_mfma_f32_16x16x32_bf16(a, bfr[mt], acc[mt], 0, 0, 0);
        a = a2;
#pragma unroll
        for (int mt = 0; mt < 8; ++mt) bfr[mt] = bfr2[mt];
    }
}

// ---- FUSED Q/K/V conv: grid (72, 6, 8); blockIdx.y -> (sel = y>>1, mh = y&1).
// sel 0: Q = W0 * XbfS (scale, MODE1); sel 1: K = W1 * XbfT (MODE1);
// sel 2: V = W2 * XbfT (MODE2). All branches block-uniform.
__global__ __launch_bounds__(256, 3) void conv_qkv_kernel(
    const bf16* __restrict__ XS, const bf16* __restrict__ XT,
    const bf16* __restrict__ Wbf,
    const float* __restrict__ qb, const float* __restrict__ kb2,
    const float* __restrict__ vb2,
    bf16* __restrict__ Qt, bf16* __restrict__ Kt, bf16* __restrict__ Vt)
{
    const int b  = blockIdx.z;
    const int sel = blockIdx.y >> 1, mh = blockIdx.y & 1;
    const int n0 = blockIdx.x * 32;
    const int w  = threadIdx.x >> 6, l = threadIdx.x & 63;
    const int wn = w & 1, wk = w >> 1;
    const int lo = l & 15, hi = l >> 4;

    __shared__ float red[2][64][36];

    const bf16* X = sel == 0 ? XS : XT;
    const float* bias = sel == 0 ? qb : sel == 1 ? kb2 : vb2;
    const float scale = sel == 0 ? SCALE_L2E : 1.0f;
    bf16* Yb = sel == 0 ? Qt : sel == 1 ? Kt : Vt;

    const int ntile = blockIdx.x * 2 + wn;
    const bf16* xp = X + ((size_t)(b * NTN + ntile) * 8) * 512 + l * 8;
    const bf16* wp = Wbf + (size_t)sel * 65536 + (size_t)mh * 32768 + l * 8;

    f32x4 acc[8];
    conv_core(xp, wp, wk, acc);

    if (wk == 1) {
#pragma unroll
        for (int mt = 0; mt < 8; ++mt)
            *(float4*)&red[wn][l][mt * 4] = make_float4(acc[mt][0], acc[mt][1],
                                                        acc[mt][2], acc[mt][3]);
    }
    __syncthreads();
    if (wk != 0) return;

#pragma unroll
    for (int mt = 0; mt < 8; ++mt) {
        float4 v = *(float4*)&red[wn][l][mt * 4];
        acc[mt][0] += v.x; acc[mt][1] += v.y; acc[mt][2] += v.z; acc[mt][3] += v.w;
    }

    const int nb = n0 + wn * 16 + hi * 4;
#pragma unroll
    for (int mt = 0; mt < 8; ++mt) {
        const int m = mh * 128 + mt * 16 + lo;
        const float bv = bias[m];
        if (sel < 2) {   // MODE 1: QF/KF fragment-order, scaled
            const int h = m >> 6, d = m & 63;
            const size_t fb = (((size_t)(b * NHEADS + h) * KCN + (nb >> 5)) * 4 + (d >> 4)) * 512
                            + ((((d >> 3) & 1) * 32) + (nb & 31)) * 8 + (d & 7);
#pragma unroll
            for (int r = 0; r < 4; ++r)
                Yb[fb + r * 8] = __float2bfloat16((acc[mt][r] + bv) * scale);
        } else {         // MODE 2: VF fragment-order
            const int h = m >> 6, dv = m & 63;
            const size_t fb = ((((size_t)(b * NHEADS + h) * KCN + (nb >> 5)) * 2 + ((nb >> 4) & 1)) * 2
                               + (dv >> 5)) * 512
                            + ((((nb >> 3) & 1) * 32) + (dv & 31)) * 8 + (nb & 7);
            uint2 u = make_uint2(pack2bf(acc[mt][0] + bv, acc[mt][1] + bv),
                                 pack2bf(acc[mt][2] + bv, acc[mt][3] + bv));
            *(uint2*)(void*)(Yb + fb) = u;
        }
    }
}

// ---- final conv (MODE 0): Op (fragment-order) x W3 -> f32 (b,c,n) out.
__global__ __launch_bounds__(256, 3) void conv_out_kernel(
    const bf16* __restrict__ X, const bf16* __restrict__ Wb,
    const float* __restrict__ bias, float* __restrict__ Yf)
{
    const int b  = blockIdx.z, mh = blockIdx.y;
    const int n0 = blockIdx.x * 32;
    const int w  = threadIdx.x >> 6, l = threadIdx.x & 63;
    const int wn = w & 1, wk = w >> 1;
    const int lo = l & 15, hi = l >> 4;

    __shared__ float red[2][64][36];

    const int ntile = blockIdx.x * 2 + wn;
    const bf16* xp = X + ((size_t)(b * NTN + ntile) * 8) * 512 + l * 8;
    const bf16* wp = Wb + (size_t)mh * 32768 + l * 8;

    f32x4 acc[8];
    conv_core(xp, wp, wk, acc);

    if (wk == 1) {
#pragma unroll
        for (int mt = 0; mt < 8; ++mt)
            *(float4*)&red[wn][l][mt * 4] = make_float4(acc[mt][0], acc[mt][1],
                                                        acc[mt][2], acc[mt][3]);
    }
    __syncthreads();
    if (wk != 0) return;

#pragma unroll
    for (int mt = 0; mt < 8; ++mt) {
        float4 v = *(float4*)&red[wn][l][mt * 4];
        acc[mt][0] += v.x; acc[mt][1] += v.y; acc[mt][2] += v.z; acc[mt][3] += v.w;
    }

    const int nb = n0 + wn * 16 + hi * 4;
#pragma unroll
    for (int mt = 0; mt < 8; ++mt) {
        const int m = mh * 128 + mt * 16 + lo;
        const float bv = bias[m];
        float4 v = make_float4(acc[mt][0] + bv, acc[mt][1] + bv,
                               acc[mt][2] + bv, acc[mt][3] + bv);
        *(float4*)(void*)(Yf + ((size_t)b * DIM + m) * NPIX + nb) = v;
    }
}

// ---- MFMA flash attention (R19, verified best): 4 waves (wq, wk); wq owns a
// 32-q subtile; wk owns 36 chunks kc = wk + 2i. Depth-1 ping-pong register
// prefetch; fragment-order operands; 2-way exact cross-wave reduction per wq.
// Output fragment-order FOp[b][ntile][kc][lane][j]. Grid (36,4,8), block 256.
__global__ __launch_bounds__(256, 3) void attn_kernel(
    const bf16* __restrict__ Qt, const bf16* __restrict__ Kt,
    const bf16* __restrict__ Vt, bf16* __restrict__ Op)
{
    const int b = blockIdx.z, h = blockIdx.y;
    const int w = threadIdx.x >> 6;
    const int wq = w & 1, wk = w >> 1;
    const int l = threadIdx.x & 63;
    const int ln = l & 31, h2 = l >> 5;
    const int bh = b * NHEADS + h;

    __shared__ float red[2][32][68];
    __shared__ float lred[2][32];

    const bf16* QB = Qt + ((size_t)bh * KCN + blockIdx.x * 2 + wq) * 2048 + l * 8;
    const bf16* KB = Kt + (size_t)bh * KCN * 2048 + l * 8;
    const bf16* VB = Vt + (size_t)bh * KCN * 2048 + l * 8;

    // Q B-frags: lane holds Q[q=nq+wq*32+ln][dk*16+h2*8+j]
    bf16x8 qf[4];
#pragma unroll
    for (int dk = 0; dk < 4; ++dk)
        qf[dk] = *(const bf16x8*)(const void*)(QB + dk * 512);

    f32x16 oacc[2];   // [dt]: O^T[d = dt*32 + row][q]
#pragma unroll
    for (int dt = 0; dt < 2; ++dt)
#pragma unroll
        for (int r = 0; r < 16; ++r) oacc[dt][r] = 0.f;
    float lsum = 0.f;

    bf16x8 kfA[4], kfB[4];
    bf16x8 vfA[2][2], vfB[2][2];

    auto load_chunk = [&](int kc_, bf16x8 (&kfD)[4], bf16x8 (&vfD)[2][2]) {
        const bf16* KBn = KB + (size_t)kc_ * 2048;
        const bf16* VBn = VB + (size_t)kc_ * 2048;
#pragma unroll
        for (int dk = 0; dk < 4; ++dk)
            kfD[dk] = *(const bf16x8*)(const void*)(KBn + dk * 512);
#pragma unroll
        for (int kb = 0; kb < 2; ++kb)
#pragma unroll
            for (int dt = 0; dt < 2; ++dt)
                vfD[kb][dt] = *(const bf16x8*)(const void*)(VBn + kb * 1024 + dt * 512);
    };

    auto compute = [&](const bf16x8 (&kfX)[4], const bf16x8 (&vfX)[2][2]) {
        f32x16 s;
#pragma unroll
        for (int r = 0; r < 16; ++r) s[r] = 0.f;
#pragma unroll
        for (int dk = 0; dk < 4; ++dk)
            s = __builtin_amdgcn_mfma_f32_32x32x16_bf16(kfX[dk], qf[dk], s, 0, 0, 0);

        // P = exp2(clamp(S)); word p covers keys 8*(p>>1)+4*h2+2*(p&1)+{0,1}
        float ls = 0.f;
        unsigned int pk[8];
#pragma unroll
        for (int p = 0; p < 8; ++p) {
            float ea = __builtin_amdgcn_exp2f(
                __builtin_amdgcn_fmed3f(s[2 * p],     -CLAMP_L2E, CLAMP_L2E));
            float eb = __builtin_amdgcn_exp2f(
                __builtin_amdgcn_fmed3f(s[2 * p + 1], -CLAMP_L2E, CLAMP_L2E));
            ls += ea + eb;
            pk[p] = pack2bf(ea, eb);
        }
        lsum += ls;

        // P^T B-frags via half-wave swaps:
        // after swap(a,b): a = {a.lo32 | b.lo32}, b = {a.hi32 | b.hi32}
        unsigned int c00 = pk[0], c02 = pk[2], c01 = pk[1], c03 = pk[3];
        unsigned int c10 = pk[4], c12 = pk[6], c11 = pk[5], c13 = pk[7];
        asm("v_permlane32_swap_b32 %0, %1" : "+v"(c00), "+v"(c02));
        asm("v_permlane32_swap_b32 %0, %1" : "+v"(c01), "+v"(c03));
        asm("v_permlane32_swap_b32 %0, %1" : "+v"(c10), "+v"(c12));
        asm("v_permlane32_swap_b32 %0, %1" : "+v"(c11), "+v"(c13));
        union { unsigned int u[4]; bf16x8 v; } pb0, pb1;
        pb0.u[0] = c00; pb0.u[1] = c01; pb0.u[2] = c02; pb0.u[3] = c03;
        pb1.u[0] = c10; pb1.u[1] = c11; pb1.u[2] = c12; pb1.u[3] = c13;

#pragma unroll
        for (int dt = 0; dt < 2; ++dt) {
            oacc[dt] = __builtin_amdgcn_mfma_f32_32x32x16_bf16(vfX[0][dt], pb0.v, oacc[dt], 0, 0, 0);
            oacc[dt] = __builtin_amdgcn_mfma_f32_32x32x16_bf16(vfX[1][dt], pb1.v, oacc[dt], 0, 0, 0);
        }
    };

    // wave (wq,wk): chunks wk, wk+2, ..., wk+70 (36 chunks), ping-pong prefetched
    load_chunk(wk, kfA, vfA);
    for (int i = 0; i < 36; i += 2) {
        load_chunk(wk + 2 * (i + 1), kfB, vfB);
        compute(kfA, vfA);
        load_chunk(i + 2 < 36 ? wk + 2 * (i + 2) : wk, kfA, vfA);  // wrap: harmless reload
        compute(kfB, vfB);
    }

    // ---- 2-way exact cross-wave reduction per wq (disjoint key sets) ----
    lsum += __shfl_xor(lsum, 32);
    if (wk == 1) {
        if (h2 == 0) lred[wq][ln] = lsum;
#pragma unroll
        for (int dt = 0; dt < 2; ++dt)
#pragma unroll
            for (int g = 0; g < 4; ++g) {
                float4 v = make_float4(oacc[dt][g * 4 + 0], oacc[dt][g * 4 + 1],
                                       oacc[dt][g * 4 + 2], oacc[dt][g * 4 + 3]);
                *(float4*)&red[wq][ln][dt * 32 + g * 8 + h2 * 4] = v;
            }
    }
    __syncthreads();

    if (wk == 0) {
#pragma unroll
        for (int dt = 0; dt < 2; ++dt)
#pragma unroll
            for (int g = 0; g < 4; ++g) {
                float4 v = *(float4*)&red[wq][ln][dt * 32 + g * 8 + h2 * 4];
                oacc[dt][g * 4 + 0] += v.x; oacc[dt][g * 4 + 1] += v.y;
                oacc[dt][g * 4 + 2] += v.z; oacc[dt][g * 4 + 3] += v.w;
            }
        const float inv = 1.f / (lsum + lred[wq][ln]);

        // store FOp fragment-order: elem (n = nq+wq*32+ln, c = h*64+dt*32+g*8+h2*4+e)
        const int ntile = blockIdx.x * 4 + wq * 2 + (ln >> 4);
        bf16* opb = Op + (((size_t)(b * NTN + ntile)) * 8 + h * 2) * 512
                  + (ln & 15) * 8 + h2 * 4;
#pragma unroll
        for (int dt = 0; dt < 2; ++dt)
#pragma unroll
            for (int g = 0; g < 4; ++g) {
                float v0 = oacc[dt][g * 4 + 0] * inv;
                float v1 = oacc[dt][g * 4 + 1] * inv;
                float v2 = oacc[dt][g * 4 + 2] * inv;
                float v3 = oacc[dt][g * 4 + 3] * inv;
                uint2 u = make_uint2(pack2bf(v0, v1), pack2bf(v2, v3));
                *(uint2*)(void*)(opb + (size_t)dt * 512 + g * 128) = u;
            }
    }
}

extern "C" void kernel_launch(void* const* d_in, const int* in_sizes, int n_in,
                              void* d_out, int out_size, void* d_ws, size_t ws_size,
                              hipStream_t stream) {
    const float* src = (const float*)d_in[0];
    const float* tgt = (const float*)d_in[1];
    const float* qw  = (const float*)d_in[2];
    const float* qb  = (const float*)d_in[3];
    const float* kw  = (const float*)d_in[4];
    const float* kb  = (const float*)d_in[5];
    const float* vw  = (const float*)d_in[6];
    const float* vb  = (const float*)d_in[7];
    const float* ow  = (const float*)d_in[8];
    const float* ob  = (const float*)d_in[9];
    float* out = (float*)d_out;

    const size_t TEN = (size_t)NBATCH * DIM * NPIX;  // 4,718,592
    bf16* Wbf  = (bf16*)d_ws;          // 4 x 65536, fragment-order
    bf16* XbfS = Wbf  + 4 * 65536;     // FX[b][ntile][kc][lane][j]
    bf16* XbfT = XbfS + TEN;
    bf16* Qt   = XbfT + TEN;           // fragment-order QF, prescaled
    bf16* Kt   = Qt   + TEN;           // fragment-order KF
    bf16* Vt   = Kt   + TEN;           // fragment-order VF
    bf16* Op   = Vt   + TEN;           // fragment-order FOp

    cvt_w_kernel<<<dim3(32, 4, 1), 256, 0, stream>>>(qw, kw, vw, ow, Wbf);
    txp_kernel<<<dim3(NPIX / 64, DIM / 64, 2 * NBATCH), 256, 0, stream>>>(src, tgt, XbfS, XbfT);

    conv_qkv_kernel<<<dim3(NPIX / 32, 6, NBATCH), 256, 0, stream>>>(
        XbfS, XbfT, Wbf, qb, kb, vb, Qt, Kt, Vt);

    attn_kernel<<<dim3(NPIX / 64, NHEADS, NBATCH), 256, 0, stream>>>(Qt, Kt, Vt, Op);

    conv_out_kernel<<<dim3(NPIX / 32, 2, NBATCH), 256, 0, stream>>>(
        Op, Wbf + 3 * 65536, ob, out);
}

// Round 24
// 120.473 us; speedup vs baseline: 1.3492x; 1.0924x over previous
//
#include <hip/hip_runtime.h>
#include <hip/hip_bf16.h>

#define DIM 256
#define NHEADS 4
#define HDIM 64
#define NPIX 2304          // 48*48
#define NBATCH 8
#define KCN 72             // NPIX/32 key chunks
#define NTN 144            // NPIX/16 n-tiles (fragment-order X/Op)
#define SCALE_L2E 0.18033688011112042f   // 0.125 * log2(e), folded into Q
#define CLAMP_L2E 8.656170245332781f     // 6.0  * log2(e)

typedef __hip_bfloat16 bf16;
typedef __bf16 bf16x8 __attribute__((ext_vector_type(8)));
typedef float  f32x4  __attribute__((ext_vector_type(4)));
typedef float  f32x16 __attribute__((ext_vector_type(16)));

__device__ __forceinline__ unsigned int pack2bf(float a, float b) {
    __hip_bfloat162 h = __float22bfloat162_rn(float2{a, b});
    union { __hip_bfloat162 h; unsigned int u; } c; c.h = h;
    return c.u;
}

// ---- 4 weight mats (256x256 f32 row-major (m,c)) -> fragment-order bf16:
// FW[mh][kc][mt][lane=hi*16+lo][j], m = mh*128+mt*16+lo, c = kc*32+hi*8+j.
__global__ __launch_bounds__(256) void cvt_w_kernel(
    const float* __restrict__ w0, const float* __restrict__ w1,
    const float* __restrict__ w2, const float* __restrict__ w3,
    bf16* __restrict__ out)
{
    const int sel = blockIdx.y;
    const float* src = sel == 0 ? w0 : sel == 1 ? w1 : sel == 2 ? w2 : w3;
    const int i = blockIdx.x * 256 + threadIdx.x;   // 8 elems per thread
    const int m = i >> 5, c0 = (i & 31) * 8;
    const int mh = m >> 7, mt = (m >> 4) & 7, lo = m & 15;
    const int kc = c0 >> 5, hi = (c0 >> 3) & 3;
    float4 a = *(const float4*)(src + i * 8);
    float4 b = *(const float4*)(src + i * 8 + 4);
    uint4 u;
    u.x = pack2bf(a.x, a.y); u.y = pack2bf(a.z, a.w);
    u.z = pack2bf(b.x, b.y); u.w = pack2bf(b.z, b.w);
    const size_t fb = (((size_t)(mh * 8 + kc)) * 8 + mt) * 512 + (hi * 16 + lo) * 8;
    *(uint4*)(void*)(out + (size_t)sel * 65536 + fb) = u;
}

// ---- src/tgt (b,c,n) f32 -> fragment-order bf16 FX[b][ntile][kc][lane][j]
// (n = ntile*16 + lo, c = kc*32 + hi*8 + j) via LDS tile transpose.
__global__ __launch_bounds__(256) void txp_kernel(
    const float* __restrict__ src, const float* __restrict__ tgt,
    bf16* __restrict__ oS, bf16* __restrict__ oT)
{
    const int b = blockIdx.z & 7;
    const float* in = (blockIdx.z >> 3) ? tgt : src;
    bf16* out = (blockIdx.z >> 3) ? oT : oS;
    const int n0 = blockIdx.x * 64, c0 = blockIdx.y * 64;
    __shared__ float tile[64][65];
    const int t = threadIdx.x;
#pragma unroll
    for (int i = 0; i < 4; ++i) {
        int idx = t + i * 256;
        int cl = idx >> 4, n4 = (idx & 15) * 4;
        float4 v = *(const float4*)(in + ((size_t)b * DIM + c0 + cl) * NPIX + n0 + n4);
        tile[cl][n4] = v.x; tile[cl][n4 + 1] = v.y;
        tile[cl][n4 + 2] = v.z; tile[cl][n4 + 3] = v.w;
    }
    __syncthreads();
#pragma unroll
    for (int i = 0; i < 2; ++i) {
        int idx = t + i * 256;
        int nl = idx >> 3, c8 = (idx & 7) * 8;
        uint4 u;
        u.x = pack2bf(tile[c8 + 0][nl], tile[c8 + 1][nl]);
        u.y = pack2bf(tile[c8 + 2][nl], tile[c8 + 3][nl]);
        u.z = pack2bf(tile[c8 + 4][nl], tile[c8 + 5][nl]);
        u.w = pack2bf(tile[c8 + 6][nl], tile[c8 + 7][nl]);
        const int n = n0 + nl, c = c0 + c8;
        const size_t fb = (((size_t)(b * NTN + (n >> 4))) * 8 + (c >> 5)) * 512
                        + ((((c >> 3) & 3) * 16) + (n & 15)) * 8;
        *(uint4*)(void*)(out + fb) = u;
    }
}

// ---- shared conv core: 32n x 128m, 4 waves (wn, wk), K-split + LDS reduce.
__device__ __forceinline__ void conv_core(
    const bf16* __restrict__ xp, const bf16* __restrict__ wp,
    int wk, f32x4 (&acc)[8])
{
#pragma unroll
    for (int mt = 0; mt < 8; ++mt) acc[mt] = (f32x4){0.f, 0.f, 0.f, 0.f};

    const int kbase = wk * 4;
    bf16x8 a = *(const bf16x8*)(const void*)(xp + (size_t)kbase * 512);
    bf16x8 bfr[8];
#pragma unroll
    for (int mt = 0; mt < 8; ++mt)
        bfr[mt] = *(const bf16x8*)(const void*)(wp + (size_t)(kbase * 8 + mt) * 512);

#pragma unroll
    for (int ki = 0; ki < 4; ++ki) {
        const int kn = kbase + ((ki + 1) & 3);   // wrap: harmless L1-hit reload
        bf16x8 a2 = *(const bf16x8*)(const void*)(xp + (size_t)kn * 512);
        bf16x8 bfr2[8];
#pragma unroll
        for (int mt = 0; mt < 8; ++mt)
            bfr2[mt] = *(const bf16x8*)(const void*)(wp + (size_t)(kn * 8 + mt) * 512);
#pragma unroll
        for (int mt = 0; mt < 8; ++mt)
            acc[mt] = __builtin_amdgcn_mfma_f32_16x16x32_bf16(a, bfr[mt], acc[mt], 0, 0, 0);
        a = a2;
#pragma unroll
        for (int mt = 0; mt < 8; ++mt) bfr[mt] = bfr2[mt];
    }
}

// ---- FUSED Q/K/V conv: grid (72, 6, 8); blockIdx.y -> (sel = y>>1, mh = y&1).
__global__ __launch_bounds__(256, 3) void conv_qkv_kernel(
    const bf16* __restrict__ XS, const bf16* __restrict__ XT,
    const bf16* __restrict__ Wbf,
    const float* __restrict__ qb, const float* __restrict__ kb2,
    const float* __restrict__ vb2,
    bf16* __restrict__ Qt, bf16* __restrict__ Kt, bf16* __restrict__ Vt)
{
    const int b  = blockIdx.z;
    const int sel = blockIdx.y >> 1, mh = blockIdx.y & 1;
    const int n0 = blockIdx.x * 32;
    const int w  = threadIdx.x >> 6, l = threadIdx.x & 63;
    const int wn = w & 1, wk = w >> 1;
    const int lo = l & 15, hi = l >> 4;

    __shared__ float red[2][64][36];

    const bf16* X = sel == 0 ? XS : XT;
    const float* bias = sel == 0 ? qb : sel == 1 ? kb2 : vb2;
    const float scale = sel == 0 ? SCALE_L2E : 1.0f;
    bf16* Yb = sel == 0 ? Qt : sel == 1 ? Kt : Vt;

    const int ntile = blockIdx.x * 2 + wn;
    const bf16* xp = X + ((size_t)(b * NTN + ntile) * 8) * 512 + l * 8;
    const bf16* wp = Wbf + (size_t)sel * 65536 + (size_t)mh * 32768 + l * 8;

    f32x4 acc[8];
    conv_core(xp, wp, wk, acc);

    if (wk == 1) {
#pragma unroll
        for (int mt = 0; mt < 8; ++mt)
            *(float4*)&red[wn][l][mt * 4] = make_float4(acc[mt][0], acc[mt][1],
                                                        acc[mt][2], acc[mt][3]);
    }
    __syncthreads();
    if (wk != 0) return;

#pragma unroll
    for (int mt = 0; mt < 8; ++mt) {
        float4 v = *(float4*)&red[wn][l][mt * 4];
        acc[mt][0] += v.x; acc[mt][1] += v.y; acc[mt][2] += v.z; acc[mt][3] += v.w;
    }

    const int nb = n0 + wn * 16 + hi * 4;
#pragma unroll
    for (int mt = 0; mt < 8; ++mt) {
        const int m = mh * 128 + mt * 16 + lo;
        const float bv = bias[m];
        if (sel < 2) {   // QF/KF fragment-order, scaled
            const int h = m >> 6, d = m & 63;
            const size_t fb = (((size_t)(b * NHEADS + h) * KCN + (nb >> 5)) * 4 + (d >> 4)) * 512
                            + ((((d >> 3) & 1) * 32) + (nb & 31)) * 8 + (d & 7);
#pragma unroll
            for (int r = 0; r < 4; ++r)
                Yb[fb + r * 8] = __float2bfloat16((acc[mt][r] + bv) * scale);
        } else {         // VF fragment-order
            const int h = m >> 6, dv = m & 63;
            const size_t fb = ((((size_t)(b * NHEADS + h) * KCN + (nb >> 5)) * 2 + ((nb >> 4) & 1)) * 2
                               + (dv >> 5)) * 512
                            + ((((nb >> 3) & 1) * 32) + (dv & 31)) * 8 + (nb & 7);
            uint2 u = make_uint2(pack2bf(acc[mt][0] + bv, acc[mt][1] + bv),
                                 pack2bf(acc[mt][2] + bv, acc[mt][3] + bv));
            *(uint2*)(void*)(Yb + fb) = u;
        }
    }
}

// ---- final conv (MODE 0): Op (fragment-order) x W3 -> f32 (b,c,n) out.
__global__ __launch_bounds__(256, 3) void conv_out_kernel(
    const bf16* __restrict__ X, const bf16* __restrict__ Wb,
    const float* __restrict__ bias, float* __restrict__ Yf)
{
    const int b  = blockIdx.z, mh = blockIdx.y;
    const int n0 = blockIdx.x * 32;
    const int w  = threadIdx.x >> 6, l = threadIdx.x & 63;
    const int wn = w & 1, wk = w >> 1;
    const int lo = l & 15, hi = l >> 4;

    __shared__ float red[2][64][36];

    const int ntile = blockIdx.x * 2 + wn;
    const bf16* xp = X + ((size_t)(b * NTN + ntile) * 8) * 512 + l * 8;
    const bf16* wp = Wb + (size_t)mh * 32768 + l * 8;

    f32x4 acc[8];
    conv_core(xp, wp, wk, acc);

    if (wk == 1) {
#pragma unroll
        for (int mt = 0; mt < 8; ++mt)
            *(float4*)&red[wn][l][mt * 4] = make_float4(acc[mt][0], acc[mt][1],
                                                        acc[mt][2], acc[mt][3]);
    }
    __syncthreads();
    if (wk != 0) return;

#pragma unroll
    for (int mt = 0; mt < 8; ++mt) {
        float4 v = *(float4*)&red[wn][l][mt * 4];
        acc[mt][0] += v.x; acc[mt][1] += v.y; acc[mt][2] += v.z; acc[mt][3] += v.w;
    }

    const int nb = n0 + wn * 16 + hi * 4;
#pragma unroll
    for (int mt = 0; mt < 8; ++mt) {
        const int m = mh * 128 + mt * 16 + lo;
        const float bv = bias[m];
        float4 v = make_float4(acc[mt][0] + bv, acc[mt][1] + bv,
                               acc[mt][2] + bv, acc[mt][3] + bv);
        *(float4*)(void*)(Yf + ((size_t)b * DIM + m) * NPIX + nb) = v;
    }
}

// ---- MFMA flash attention: 128-q blocks to HALVE K/V L2 traffic.
// 4 waves (wq, wk): wq owns 64 q (2 subtiles qs, R15-verified loop) of
// q-tile qt = blockIdx.x; wk owns 36 chunks kc = wk + 2i (R19-verified).
// K/V fragments of each chunk shared across both qs subtiles -> per-query
// K/V traffic halved vs R19 (1.36 GB -> 0.68 GB L2). Depth-1 ping-pong.
// 2-way exact cross-wave reduction per (wq, qs). Grid (18,4,8), block 256.
__global__ __launch_bounds__(256, 2) void attn_kernel(
    const bf16* __restrict__ Qt, const bf16* __restrict__ Kt,
    const bf16* __restrict__ Vt, bf16* __restrict__ Op)
{
    const int b = blockIdx.z, h = blockIdx.y;
    const int w = threadIdx.x >> 6;
    const int wq = w & 1, wk = w >> 1;
    const int l = threadIdx.x & 63;
    const int ln = l & 31, h2 = l >> 5;
    const int bh = b * NHEADS + h;
    const int qt = blockIdx.x;

    __shared__ float red[2][2][32][68];   // [wq][qs][q][d]
    __shared__ float lred[2][2][32];      // [wq][qs][q]

    const bf16* QB = Qt + ((size_t)bh * KCN + qt * 4 + wq * 2) * 2048 + l * 8;
    const bf16* KB = Kt + (size_t)bh * KCN * 2048 + l * 8;
    const bf16* VB = Vt + (size_t)bh * KCN * 2048 + l * 8;

    // Q B-frags: lane holds Q[q = qt*128 + wq*64 + qs*32 + ln][dk*16+h2*8+j]
    bf16x8 qf[2][4];
#pragma unroll
    for (int qs = 0; qs < 2; ++qs)
#pragma unroll
        for (int dk = 0; dk < 4; ++dk)
            qf[qs][dk] = *(const bf16x8*)(const void*)(QB + qs * 2048 + dk * 512);

    f32x16 oacc[2][2];   // [qs][dt]
#pragma unroll
    for (int qs = 0; qs < 2; ++qs)
#pragma unroll
        for (int dt = 0; dt < 2; ++dt)
#pragma unroll
            for (int r = 0; r < 16; ++r) oacc[qs][dt][r] = 0.f;
    float lsum[2] = {0.f, 0.f};

    bf16x8 kfA[4], kfB[4];
    bf16x8 vfA[2][2], vfB[2][2];

    auto load_chunk = [&](int kc_, bf16x8 (&kfD)[4], bf16x8 (&vfD)[2][2]) {
        const bf16* KBn = KB + (size_t)kc_ * 2048;
        const bf16* VBn = VB + (size_t)kc_ * 2048;
#pragma unroll
        for (int dk = 0; dk < 4; ++dk)
            kfD[dk] = *(const bf16x8*)(const void*)(KBn + dk * 512);
#pragma unroll
        for (int kb = 0; kb < 2; ++kb)
#pragma unroll
            for (int dt = 0; dt < 2; ++dt)
                vfD[kb][dt] = *(const bf16x8*)(const void*)(VBn + kb * 1024 + dt * 512);
    };

    auto compute = [&](const bf16x8 (&kfX)[4], const bf16x8 (&vfX)[2][2]) {
#pragma unroll
        for (int qs = 0; qs < 2; ++qs) {
            f32x16 s;
#pragma unroll
            for (int r = 0; r < 16; ++r) s[r] = 0.f;
#pragma unroll
            for (int dk = 0; dk < 4; ++dk)
                s = __builtin_amdgcn_mfma_f32_32x32x16_bf16(kfX[dk], qf[qs][dk], s, 0, 0, 0);

            // P = exp2(clamp(S)); word p covers keys 8*(p>>1)+4*h2+2*(p&1)+{0,1}
            float ls = 0.f;
            unsigned int pk[8];
#pragma unroll
            for (int p = 0; p < 8; ++p) {
                float ea = __builtin_amdgcn_exp2f(
                    __builtin_amdgcn_fmed3f(s[2 * p],     -CLAMP_L2E, CLAMP_L2E));
                float eb = __builtin_amdgcn_exp2f(
                    __builtin_amdgcn_fmed3f(s[2 * p + 1], -CLAMP_L2E, CLAMP_L2E));
                ls += ea + eb;
                pk[p] = pack2bf(ea, eb);
            }
            lsum[qs] += ls;

            // P^T B-frags via half-wave swaps
            unsigned int c00 = pk[0], c02 = pk[2], c01 = pk[1], c03 = pk[3];
            unsigned int c10 = pk[4], c12 = pk[6], c11 = pk[5], c13 = pk[7];
            asm("v_permlane32_swap_b32 %0, %1" : "+v"(c00), "+v"(c02));
            asm("v_permlane32_swap_b32 %0, %1" : "+v"(c01), "+v"(c03));
            asm("v_permlane32_swap_b32 %0, %1" : "+v"(c10), "+v"(c12));
            asm("v_permlane32_swap_b32 %0, %1" : "+v"(c11), "+v"(c13));
            union { unsigned int u[4]; bf16x8 v; } pb0, pb1;
            pb0.u[0] = c00; pb0.u[1] = c01; pb0.u[2] = c02; pb0.u[3] = c03;
            pb1.u[0] = c10; pb1.u[1] = c11; pb1.u[2] = c12; pb1.u[3] = c13;

#pragma unroll
            for (int dt = 0; dt < 2; ++dt) {
                oacc[qs][dt] = __builtin_amdgcn_mfma_f32_32x32x16_bf16(vfX[0][dt], pb0.v, oacc[qs][dt], 0, 0, 0);
                oacc[qs][dt] = __builtin_amdgcn_mfma_f32_32x32x16_bf16(vfX[1][dt], pb1.v, oacc[qs][dt], 0, 0, 0);
            }
        }
    };

    // wave (wq,wk): chunks wk, wk+2, ..., wk+70 (36 chunks), ping-pong prefetched
    load_chunk(wk, kfA, vfA);
    for (int i = 0; i < 36; i += 2) {
        load_chunk(wk + 2 * (i + 1), kfB, vfB);
        compute(kfA, vfA);
        load_chunk(i + 2 < 36 ? wk + 2 * (i + 2) : wk, kfA, vfA);  // wrap: harmless reload
        compute(kfB, vfB);
    }

    // ---- 2-way exact cross-wave reduction per (wq, qs) ----
#pragma unroll
    for (int qs = 0; qs < 2; ++qs) lsum[qs] += __shfl_xor(lsum[qs], 32);
    if (wk == 1) {
        if (h2 == 0) { lred[wq][0][ln] = lsum[0]; lred[wq][1][ln] = lsum[1]; }
#pragma unroll
        for (int qs = 0; qs < 2; ++qs)
#pragma unroll
            for (int dt = 0; dt < 2; ++dt)
#pragma unroll
                for (int g = 0; g < 4; ++g) {
                    float4 v = make_float4(oacc[qs][dt][g * 4 + 0], oacc[qs][dt][g * 4 + 1],
                                           oacc[qs][dt][g * 4 + 2], oacc[qs][dt][g * 4 + 3]);
                    *(float4*)&red[wq][qs][ln][dt * 32 + g * 8 + h2 * 4] = v;
                }
    }
    __syncthreads();

    if (wk == 0) {
#pragma unroll
        for (int qs = 0; qs < 2; ++qs) {
#pragma unroll
            for (int dt = 0; dt < 2; ++dt)
#pragma unroll
                for (int g = 0; g < 4; ++g) {
                    float4 v = *(float4*)&red[wq][qs][ln][dt * 32 + g * 8 + h2 * 4];
                    oacc[qs][dt][g * 4 + 0] += v.x; oacc[qs][dt][g * 4 + 1] += v.y;
                    oacc[qs][dt][g * 4 + 2] += v.z; oacc[qs][dt][g * 4 + 3] += v.w;
                }
            const float inv = 1.f / (lsum[qs] + lred[wq][qs][ln]);

            // store FOp: n = qt*128 + wq*64 + qs*32 + ln
            const int ntile = qt * 8 + wq * 4 + qs * 2 + (ln >> 4);
            bf16* opb = Op + (((size_t)(b * NTN + ntile)) * 8 + h * 2) * 512
                      + (ln & 15) * 8 + h2 * 4;
#pragma unroll
            for (int dt = 0; dt < 2; ++dt)
#pragma unroll
                for (int g = 0; g < 4; ++g) {
                    float v0 = oacc[qs][dt][g * 4 + 0] * inv;
                    float v1 = oacc[qs][dt][g * 4 + 1] * inv;
                    float v2 = oacc[qs][dt][g * 4 + 2] * inv;
                    float v3 = oacc[qs][dt][g * 4 + 3] * inv;
                    uint2 u = make_uint2(pack2bf(v0, v1), pack2bf(v2, v3));
                    *(uint2*)(void*)(opb + (size_t)dt * 512 + g * 128) = u;
                }
        }
    }
}

extern "C" void kernel_launch(void* const* d_in, const int* in_sizes, int n_in,
                              void* d_out, int out_size, void* d_ws, size_t ws_size,
                              hipStream_t stream) {
    const float* src = (const float*)d_in[0];
    const float* tgt = (const float*)d_in[1];
    const float* qw  = (const float*)d_in[2];
    const float* qb  = (const float*)d_in[3];
    const float* kw  = (const float*)d_in[4];
    const float* kb  = (const float*)d_in[5];
    const float* vw  = (const float*)d_in[6];
    const float* vb  = (const float*)d_in[7];
    const float* ow  = (const float*)d_in[8];
    const float* ob  = (const float*)d_in[9];
    float* out = (float*)d_out;

    const size_t TEN = (size_t)NBATCH * DIM * NPIX;  // 4,718,592
    bf16* Wbf  = (bf16*)d_ws;          // 4 x 65536, fragment-order
    bf16* XbfS = Wbf  + 4 * 65536;     // FX[b][ntile][kc][lane][j]
    bf16* XbfT = XbfS + TEN;
    bf16* Qt   = XbfT + TEN;           // fragment-order QF, prescaled
    bf16* Kt   = Qt   + TEN;           // fragment-order KF
    bf16* Vt   = Kt   + TEN;           // fragment-order VF
    bf16* Op   = Vt   + TEN;           // fragment-order FOp

    cvt_w_kernel<<<dim3(32, 4, 1), 256, 0, stream>>>(qw, kw, vw, ow, Wbf);
    txp_kernel<<<dim3(NPIX / 64, DIM / 64, 2 * NBATCH), 256, 0, stream>>>(src, tgt, XbfS, XbfT);

    conv_qkv_kernel<<<dim3(NPIX / 32, 6, NBATCH), 256, 0, stream>>>(
        XbfS, XbfT, Wbf, qb, kb, vb, Qt, Kt, Vt);

    attn_kernel<<<dim3(NPIX / 128, NHEADS, NBATCH), 256, 0, stream>>>(Qt, Kt, Vt, Op);

    conv_out_kernel<<<dim3(NPIX / 32, 2, NBATCH), 256, 0, stream>>>(
        Op, Wbf + 3 * 65536, ob, out);
}

// Round 26
// 119.499 us; speedup vs baseline: 1.3602x; 1.0082x over previous
//
#include <hip/hip_runtime.h>
#include <hip/hip_bf16.h>

#define DIM 256
#define NHEADS 4
#define HDIM 64
#define NPIX 2304          // 48*48
#define NBATCH 8
#define KCN 72             // NPIX/32 key chunks
#define NTN 144            // NPIX/16 n-tiles (fragment-order X/Op)
#define SCALE_L2E 0.18033688011112042f   // 0.125 * log2(e), folded into Q
#define CLAMP_L2E 8.656170245332781f     // 6.0  * log2(e)

typedef __hip_bfloat16 bf16;
typedef __bf16 bf16x8 __attribute__((ext_vector_type(8)));
typedef float  f32x4  __attribute__((ext_vector_type(4)));
typedef float  f32x16 __attribute__((ext_vector_type(16)));

__device__ __forceinline__ unsigned int pack2bf(float a, float b) {
    __hip_bfloat162 h = __float22bfloat162_rn(float2{a, b});
    union { __hip_bfloat162 h; unsigned int u; } c; c.h = h;
    return c.u;
}

// ---- 4 weight mats (256x256 f32 row-major (m,c)) -> fragment-order bf16:
// FW[mh][kc][mt][lane=hi*16+lo][j], m = mh*128+mt*16+lo, c = kc*32+hi*8+j.
__global__ __launch_bounds__(256) void cvt_w_kernel(
    const float* __restrict__ w0, const float* __restrict__ w1,
    const float* __restrict__ w2, const float* __restrict__ w3,
    bf16* __restrict__ out)
{
    const int sel = blockIdx.y;
    const float* src = sel == 0 ? w0 : sel == 1 ? w1 : sel == 2 ? w2 : w3;
    const int i = blockIdx.x * 256 + threadIdx.x;   // 8 elems per thread
    const int m = i >> 5, c0 = (i & 31) * 8;
    const int mh = m >> 7, mt = (m >> 4) & 7, lo = m & 15;
    const int kc = c0 >> 5, hi = (c0 >> 3) & 3;
    float4 a = *(const float4*)(src + i * 8);
    float4 b = *(const float4*)(src + i * 8 + 4);
    uint4 u;
    u.x = pack2bf(a.x, a.y); u.y = pack2bf(a.z, a.w);
    u.z = pack2bf(b.x, b.y); u.w = pack2bf(b.z, b.w);
    const size_t fb = (((size_t)(mh * 8 + kc)) * 8 + mt) * 512 + (hi * 16 + lo) * 8;
    *(uint4*)(void*)(out + (size_t)sel * 65536 + fb) = u;
}

// ---- FUSED transpose + Q/K/V conv. Grid (72, 6, 8); y -> (sel=y>>1, mh=y&1).
// Phase 1: load f32 X-tile (256c x 32n) from src/tgt (b,c,n) into LDS tile.
// Phase 2: pack to fragment-order bf16 LDS fx[wn][kc][lane][j].
// Phase 3: verified conv core (A from LDS, W global, K-split wk, LDS reduce).
// sel 0: Q = W0 * src (scale); sel 1: K = W1 * tgt; sel 2: V = W2 * tgt.
__global__ __launch_bounds__(256, 3) void conv_qkv_kernel(
    const float* __restrict__ srcf, const float* __restrict__ tgtf,
    const bf16* __restrict__ Wbf,
    const float* __restrict__ qb, const float* __restrict__ kb2,
    const float* __restrict__ vb2,
    bf16* __restrict__ Qt, bf16* __restrict__ Kt, bf16* __restrict__ Vt)
{
    __shared__ __align__(16) unsigned char smem[50176];
    float (*tile)[33] = reinterpret_cast<float(*)[33]>(smem);          // 33792 B
    bf16* fx = reinterpret_cast<bf16*>(smem + 33792);                  // 16384 B
    float (*red)[36] = reinterpret_cast<float(*)[36]>(smem);           // aliases tile

    const int b  = blockIdx.z;
    const int sel = blockIdx.y >> 1, mh = blockIdx.y & 1;
    const int n0 = blockIdx.x * 32;
    const int t  = threadIdx.x;
    const int w  = t >> 6, l = t & 63;
    const int wn = w & 1, wk = w >> 1;
    const int lo = l & 15, hi = l >> 4;

    const float* Xf = sel == 0 ? srcf : tgtf;
    const float* bias = sel == 0 ? qb : sel == 1 ? kb2 : vb2;
    const float scale = sel == 0 ? SCALE_L2E : 1.0f;
    bf16* Yb = sel == 0 ? Qt : sel == 1 ? Kt : Vt;

    // ---- phase 1: f32 (c,n) tile load, 8 threads/row x float4
    {
        const int trow = t >> 3, tf = t & 7;
#pragma unroll
        for (int p = 0; p < 8; ++p) {
            const int c = trow + p * 32;
            float4 v = *(const float4*)(Xf + ((size_t)b * DIM + c) * NPIX + n0 + tf * 4);
            tile[c][tf * 4 + 0] = v.x; tile[c][tf * 4 + 1] = v.y;
            tile[c][tf * 4 + 2] = v.z; tile[c][tf * 4 + 3] = v.w;
        }
    }
    __syncthreads();

    // ---- phase 2: pack fragment-order bf16: fx[wn][kc][hi*16+lo][j]
    {
        const int pwn = t >> 7, r = t & 127;
        const int pkc = r >> 4, phi = (r >> 2) & 3, plo0 = (r & 3) * 4;
#pragma unroll
        for (int lo2 = 0; lo2 < 4; ++lo2) {
            const int plo = plo0 + lo2;
            const int row = pkc * 32 + phi * 8;
            const int col = pwn * 16 + plo;
            uint4 u;
            u.x = pack2bf(tile[row + 0][col], tile[row + 1][col]);
            u.y = pack2bf(tile[row + 2][col], tile[row + 3][col]);
            u.z = pack2bf(tile[row + 4][col], tile[row + 5][col]);
            u.w = pack2bf(tile[row + 6][col], tile[row + 7][col]);
            *(uint4*)(void*)&fx[(size_t)pwn * 4096 + pkc * 512 + (phi * 16 + plo) * 8] = u;
        }
    }
    __syncthreads();

    // ---- phase 3: conv core (A from LDS fx[wn], W global, K-split wk)
    const bf16* fxw = fx + (size_t)wn * 4096;
    const bf16* wp  = Wbf + (size_t)sel * 65536 + (size_t)mh * 32768 + l * 8;

    f32x4 acc[8];
#pragma unroll
    for (int mt = 0; mt < 8; ++mt) acc[mt] = (f32x4){0.f, 0.f, 0.f, 0.f};

    const int kbase = wk * 4;
    bf16x8 a = *(const bf16x8*)(const void*)(fxw + kbase * 512 + l * 8);
    bf16x8 bfr[8];
#pragma unroll
    for (int mt = 0; mt < 8; ++mt)
        bfr[mt] = *(const bf16x8*)(const void*)(wp + (size_t)(kbase * 8 + mt) * 512);

#pragma unroll
    for (int ki = 0; ki < 4; ++ki) {
        const int kn = kbase + ((ki + 1) & 3);   // wrap: harmless reload
        bf16x8 a2 = *(const bf16x8*)(const void*)(fxw + kn * 512 + l * 8);
        bf16x8 bfr2[8];
#pragma unroll
        for (int mt = 0; mt < 8; ++mt)
            bfr2[mt] = *(const bf16x8*)(const void*)(wp + (size_t)(kn * 8 + mt) * 512);
#pragma unroll
        for (int mt = 0; mt < 8; ++mt)
            acc[mt] = __builtin_amdgcn_mfma_f32_16x16x32_bf16(a, bfr[mt], acc[mt], 0, 0, 0);
        a = a2;
#pragma unroll
        for (int mt = 0; mt < 8; ++mt) bfr[mt] = bfr2[mt];
    }

    // ---- exact cross-wave K-reduction (red aliases tile; barrier above
    // guarantees all phase-2 tile reads completed block-wide)
    __syncthreads();
    if (wk == 1) {
#pragma unroll
        for (int mt = 0; mt < 8; ++mt)
            *(float4*)&red[wn * 64 + l][mt * 4] = make_float4(acc[mt][0], acc[mt][1],
                                                              acc[mt][2], acc[mt][3]);
    }
    __syncthreads();
    if (wk != 0) return;

#pragma unroll
    for (int mt = 0; mt < 8; ++mt) {
        float4 v = *(float4*)&red[wn * 64 + l][mt * 4];
        acc[mt][0] += v.x; acc[mt][1] += v.y; acc[mt][2] += v.z; acc[mt][3] += v.w;
    }

    const int nb = n0 + wn * 16 + hi * 4;
#pragma unroll
    for (int mt = 0; mt < 8; ++mt) {
        const int m = mh * 128 + mt * 16 + lo;
        const float bv = bias[m];
        if (sel < 2) {   // QF/KF fragment-order, scaled
            const int h = m >> 6, d = m & 63;
            const size_t fb = (((size_t)(b * NHEADS + h) * KCN + (nb >> 5)) * 4 + (d >> 4)) * 512
                            + ((((d >> 3) & 1) * 32) + (nb & 31)) * 8 + (d & 7);
#pragma unroll
            for (int r = 0; r < 4; ++r)
                Yb[fb + r * 8] = __float2bfloat16((acc[mt][r] + bv) * scale);
        } else {         // VF fragment-order
            const int h = m >> 6, dv = m & 63;
            const size_t fb = ((((size_t)(b * NHEADS + h) * KCN + (nb >> 5)) * 2 + ((nb >> 4) & 1)) * 2
                               + (dv >> 5)) * 512
                            + ((((nb >> 3) & 1) * 32) + (dv & 31)) * 8 + (nb & 7);
            uint2 u = make_uint2(pack2bf(acc[mt][0] + bv, acc[mt][1] + bv),
                                 pack2bf(acc[mt][2] + bv, acc[mt][3] + bv));
            *(uint2*)(void*)(Yb + fb) = u;
        }
    }
}

// ---- final conv: Op (fragment-order) x W3 -> f32 (b,c,n) out.
__global__ __launch_bounds__(256, 3) void conv_out_kernel(
    const bf16* __restrict__ X, const bf16* __restrict__ Wb,
    const float* __restrict__ bias, float* __restrict__ Yf)
{
    const int b  = blockIdx.z, mh = blockIdx.y;
    const int n0 = blockIdx.x * 32;
    const int w  = threadIdx.x >> 6, l = threadIdx.x & 63;
    const int wn = w & 1, wk = w >> 1;
    const int lo = l & 15, hi = l >> 4;

    __shared__ float red[2][64][36];

    const int ntile = blockIdx.x * 2 + wn;
    const bf16* xp = X + ((size_t)(b * NTN + ntile) * 8) * 512 + l * 8;
    const bf16* wp = Wb + (size_t)mh * 32768 + l * 8;

    f32x4 acc[8];
#pragma unroll
    for (int mt = 0; mt < 8; ++mt) acc[mt] = (f32x4){0.f, 0.f, 0.f, 0.f};

    const int kbase = wk * 4;
    bf16x8 a = *(const bf16x8*)(const void*)(xp + (size_t)kbase * 512);
    bf16x8 bfr[8];
#pragma unroll
    for (int mt = 0; mt < 8; ++mt)
        bfr[mt] = *(const bf16x8*)(const void*)(wp + (size_t)(kbase * 8 + mt) * 512);

#pragma unroll
    for (int ki = 0; ki < 4; ++ki) {
        const int kn = kbase + ((ki + 1) & 3);
        bf16x8 a2 = *(const bf16x8*)(const void*)(xp + (size_t)kn * 512);
        bf16x8 bfr2[8];
#pragma unroll
        for (int mt = 0; mt < 8; ++mt)
            bfr2[mt] = *(const bf16x8*)(const void*)(wp + (size_t)(kn * 8 + mt) * 512);
#pragma unroll
        for (int mt = 0; mt < 8; ++mt)
            acc[mt] = __builtin_amdgcn_mfma_f32_16x16x32_bf16(a, bfr[mt], acc[mt], 0, 0, 0);
        a = a2;
#pragma unroll
        for (int mt = 0; mt < 8; ++mt) bfr[mt] = bfr2[mt];
    }

    if (wk == 1) {
#pragma unroll
        for (int mt = 0; mt < 8; ++mt)
            *(float4*)&red[wn][l][mt * 4] = make_float4(acc[mt][0], acc[mt][1],
                                                        acc[mt][2], acc[mt][3]);
    }
    __syncthreads();
    if (wk != 0) return;

#pragma unroll
    for (int mt = 0; mt < 8; ++mt) {
        float4 v = *(float4*)&red[wn][l][mt * 4];
        acc[mt][0] += v.x; acc[mt][1] += v.y; acc[mt][2] += v.z; acc[mt][3] += v.w;
    }

    const int nb = n0 + wn * 16 + hi * 4;
#pragma unroll
    for (int mt = 0; mt < 8; ++mt) {
        const int m = mh * 128 + mt * 16 + lo;
        const float bv = bias[m];
        float4 v = make_float4(acc[mt][0] + bv, acc[mt][1] + bv,
                               acc[mt][2] + bv, acc[mt][3] + bv);
        *(float4*)(void*)(Yf + ((size_t)b * DIM + m) * NPIX + nb) = v;
    }
}

// ---- MFMA flash attention (R24, verified): 128-q blocks, 4 waves (wq, wk):
// wq owns 64 q (2 subtiles qs); wk owns 36 chunks kc = wk + 2i. Depth-1
// ping-pong; fragment-order operands; 2-way reduction per (wq, qs).
// Grid (18,4,8), block 256.
__global__ __launch_bounds__(256, 2) void attn_kernel(
    const bf16* __restrict__ Qt, const bf16* __restrict__ Kt,
    const bf16* __restrict__ Vt, bf16* __restrict__ Op)
{
    const int b = blockIdx.z, h = blockIdx.y;
    const int w = threadIdx.x >> 6;
    const int wq = w & 1, wk = w >> 1;
    const int l = threadIdx.x & 63;
    const int ln = l & 31, h2 = l >> 5;
    const int bh = b * NHEADS + h;
    const int qt = blockIdx.x;

    __shared__ float red[2][2][32][68];   // [wq][qs][q][d]
    __shared__ float lred[2][2][32];      // [wq][qs][q]

    const bf16* QB = Qt + ((size_t)bh * KCN + qt * 4 + wq * 2) * 2048 + l * 8;
    const bf16* KB = Kt + (size_t)bh * KCN * 2048 + l * 8;
    const bf16* VB = Vt + (size_t)bh * KCN * 2048 + l * 8;

    bf16x8 qf[2][4];
#pragma unroll
    for (int qs = 0; qs < 2; ++qs)
#pragma unroll
        for (int dk = 0; dk < 4; ++dk)
            qf[qs][dk] = *(const bf16x8*)(const void*)(QB + qs * 2048 + dk * 512);

    f32x16 oacc[2][2];
#pragma unroll
    for (int qs = 0; qs < 2; ++qs)
#pragma unroll
        for (int dt = 0; dt < 2; ++dt)
#pragma unroll
            for (int r = 0; r < 16; ++r) oacc[qs][dt][r] = 0.f;
    float lsum[2] = {0.f, 0.f};

    bf16x8 kfA[4], kfB[4];
    bf16x8 vfA[2][2], vfB[2][2];

    auto load_chunk = [&](int kc_, bf16x8 (&kfD)[4], bf16x8 (&vfD)[2][2]) {
        const bf16* KBn = KB + (size_t)kc_ * 2048;
        const bf16* VBn = VB + (size_t)kc_ * 2048;
#pragma unroll
        for (int dk = 0; dk < 4; ++dk)
            kfD[dk] = *(const bf16x8*)(const void*)(KBn + dk * 512);
#pragma unroll
        for (int kb = 0; kb < 2; ++kb)
#pragma unroll
            for (int dt = 0; dt < 2; ++dt)
                vfD[kb][dt] = *(const bf16x8*)(const void*)(VBn + kb * 1024 + dt * 512);
    };

    auto compute = [&](const bf16x8 (&kfX)[4], const bf16x8 (&vfX)[2][2]) {
#pragma unroll
        for (int qs = 0; qs < 2; ++qs) {
            f32x16 s;
#pragma unroll
            for (int r = 0; r < 16; ++r) s[r] = 0.f;
#pragma unroll
            for (int dk = 0; dk < 4; ++dk)
                s = __builtin_amdgcn_mfma_f32_32x32x16_bf16(kfX[dk], qf[qs][dk], s, 0, 0, 0);

            float ls = 0.f;
            unsigned int pk[8];
#pragma unroll
            for (int p = 0; p < 8; ++p) {
                float ea = __builtin_amdgcn_exp2f(
                    __builtin_amdgcn_fmed3f(s[2 * p],     -CLAMP_L2E, CLAMP_L2E));
                float eb = __builtin_amdgcn_exp2f(
                    __builtin_amdgcn_fmed3f(s[2 * p + 1], -CLAMP_L2E, CLAMP_L2E));
                ls += ea + eb;
                pk[p] = pack2bf(ea, eb);
            }
            lsum[qs] += ls;

            unsigned int c00 = pk[0], c02 = pk[2], c01 = pk[1], c03 = pk[3];
            unsigned int c10 = pk[4], c12 = pk[6], c11 = pk[5], c13 = pk[7];
            asm("v_permlane32_swap_b32 %0, %1" : "+v"(c00), "+v"(c02));
            asm("v_permlane32_swap_b32 %0, %1" : "+v"(c01), "+v"(c03));
            asm("v_permlane32_swap_b32 %0, %1" : "+v"(c10), "+v"(c12));
            asm("v_permlane32_swap_b32 %0, %1" : "+v"(c11), "+v"(c13));
            union { unsigned int u[4]; bf16x8 v; } pb0, pb1;
            pb0.u[0] = c00; pb0.u[1] = c01; pb0.u[2] = c02; pb0.u[3] = c03;
            pb1.u[0] = c10; pb1.u[1] = c11; pb1.u[2] = c12; pb1.u[3] = c13;

#pragma unroll
            for (int dt = 0; dt < 2; ++dt) {
                oacc[qs][dt] = __builtin_amdgcn_mfma_f32_32x32x16_bf16(vfX[0][dt], pb0.v, oacc[qs][dt], 0, 0, 0);
                oacc[qs][dt] = __builtin_amdgcn_mfma_f32_32x32x16_bf16(vfX[1][dt], pb1.v, oacc[qs][dt], 0, 0, 0);
            }
        }
    };

    load_chunk(wk, kfA, vfA);
    for (int i = 0; i < 36; i += 2) {
        load_chunk(wk + 2 * (i + 1), kfB, vfB);
        compute(kfA, vfA);
        load_chunk(i + 2 < 36 ? wk + 2 * (i + 2) : wk, kfA, vfA);
        compute(kfB, vfB);
    }

#pragma unroll
    for (int qs = 0; qs < 2; ++qs) lsum[qs] += __shfl_xor(lsum[qs], 32);
    if (wk == 1) {
        if (h2 == 0) { lred[wq][0][ln] = lsum[0]; lred[wq][1][ln] = lsum[1]; }
#pragma unroll
        for (int qs = 0; qs < 2; ++qs)
#pragma unroll
            for (int dt = 0; dt < 2; ++dt)
#pragma unroll
                for (int g = 0; g < 4; ++g) {
                    float4 v = make_float4(oacc[qs][dt][g * 4 + 0], oacc[qs][dt][g * 4 + 1],
                                           oacc[qs][dt][g * 4 + 2], oacc[qs][dt][g * 4 + 3]);
                    *(float4*)&red[wq][qs][ln][dt * 32 + g * 8 + h2 * 4] = v;
                }
    }
    __syncthreads();

    if (wk == 0) {
#pragma unroll
        for (int qs = 0; qs < 2; ++qs) {
#pragma unroll
            for (int dt = 0; dt < 2; ++dt)
#pragma unroll
                for (int g = 0; g < 4; ++g) {
                    float4 v = *(float4*)&red[wq][qs][ln][dt * 32 + g * 8 + h2 * 4];
                    oacc[qs][dt][g * 4 + 0] += v.x; oacc[qs][dt][g * 4 + 1] += v.y;
                    oacc[qs][dt][g * 4 + 2] += v.z; oacc[qs][dt][g * 4 + 3] += v.w;
                }
            const float inv = 1.f / (lsum[qs] + lred[wq][qs][ln]);

            const int ntile = qt * 8 + wq * 4 + qs * 2 + (ln >> 4);
            bf16* opb = Op + (((size_t)(b * NTN + ntile)) * 8 + h * 2) * 512
                      + (ln & 15) * 8 + h2 * 4;
#pragma unroll
            for (int dt = 0; dt < 2; ++dt)
#pragma unroll
                for (int g = 0; g < 4; ++g) {
                    float v0 = oacc[qs][dt][g * 4 + 0] * inv;
                    float v1 = oacc[qs][dt][g * 4 + 1] * inv;
                    float v2 = oacc[qs][dt][g * 4 + 2] * inv;
                    float v3 = oacc[qs][dt][g * 4 + 3] * inv;
                    uint2 u = make_uint2(pack2bf(v0, v1), pack2bf(v2, v3));
                    *(uint2*)(void*)(opb + (size_t)dt * 512 + g * 128) = u;
                }
        }
    }
}

extern "C" void kernel_launch(void* const* d_in, const int* in_sizes, int n_in,
                              void* d_out, int out_size, void* d_ws, size_t ws_size,
                              hipStream_t stream) {
    const float* src = (const float*)d_in[0];
    const float* tgt = (const float*)d_in[1];
    const float* qw  = (const float*)d_in[2];
    const float* qb  = (const float*)d_in[3];
    const float* kw  = (const float*)d_in[4];
    const float* kb  = (const float*)d_in[5];
    const float* vw  = (const float*)d_in[6];
    const float* vb  = (const float*)d_in[7];
    const float* ow  = (const float*)d_in[8];
    const float* ob  = (const float*)d_in[9];
    float* out = (float*)d_out;

    const size_t TEN = (size_t)NBATCH * DIM * NPIX;  // 4,718,592
    bf16* Wbf  = (bf16*)d_ws;          // 4 x 65536, fragment-order
    bf16* Qt   = Wbf + 4 * 65536;      // fragment-order QF, prescaled
    bf16* Kt   = Qt  + TEN;            // fragment-order KF
    bf16* Vt   = Kt  + TEN;            // fragment-order VF
    bf16* Op   = Vt  + TEN;            // fragment-order FOp

    cvt_w_kernel<<<dim3(32, 4, 1), 256, 0, stream>>>(qw, kw, vw, ow, Wbf);

    conv_qkv_kernel<<<dim3(NPIX / 32, 6, NBATCH), 256, 0, stream>>>(
        src, tgt, Wbf, qb, kb, vb, Qt, Kt, Vt);

    attn_kernel<<<dim3(NPIX / 128, NHEADS, NBATCH), 256, 0, stream>>>(Qt, Kt, Vt, Op);

    conv_out_kernel<<<dim3(NPIX / 32, 2, NBATCH), 256, 0, stream>>>(
        Op, Wbf + 3 * 65536, ob, out);
}

// Round 27
// 116.054 us; speedup vs baseline: 1.4006x; 1.0297x over previous
//
#include <hip/hip_runtime.h>
#include <hip/hip_bf16.h>

#define DIM 256
#define NHEADS 4
#define HDIM 64
#define NPIX 2304          // 48*48
#define NBATCH 8
#define KCN 72             // NPIX/32 key chunks
#define NTN 144            // NPIX/16 n-tiles (fragment-order X/Op)
#define SCALE_L2E 0.18033688011112042f   // 0.125 * log2(e), folded into Q
#define CLAMP_L2E 8.656170245332781f     // 6.0  * log2(e)

typedef __hip_bfloat16 bf16;
typedef __bf16 bf16x8 __attribute__((ext_vector_type(8)));
typedef float  f32x4  __attribute__((ext_vector_type(4)));
typedef float  f32x16 __attribute__((ext_vector_type(16)));

__device__ __forceinline__ unsigned int pack2bf(float a, float b) {
    __hip_bfloat162 h = __float22bfloat162_rn(float2{a, b});
    union { __hip_bfloat162 h; unsigned int u; } c; c.h = h;
    return c.u;
}

// ---- 4 weight mats (256x256 f32 row-major (m,c)) -> fragment-order bf16:
// FW[mh][kc][mt][lane=hi*16+lo][j], m = mh*128+mt*16+lo, c = kc*32+hi*8+j.
__global__ __launch_bounds__(256) void cvt_w_kernel(
    const float* __restrict__ w0, const float* __restrict__ w1,
    const float* __restrict__ w2, const float* __restrict__ w3,
    bf16* __restrict__ out)
{
    const int sel = blockIdx.y;
    const float* src = sel == 0 ? w0 : sel == 1 ? w1 : sel == 2 ? w2 : w3;
    const int i = blockIdx.x * 256 + threadIdx.x;   // 8 elems per thread
    const int m = i >> 5, c0 = (i & 31) * 8;
    const int mh = m >> 7, mt = (m >> 4) & 7, lo = m & 15;
    const int kc = c0 >> 5, hi = (c0 >> 3) & 3;
    float4 a = *(const float4*)(src + i * 8);
    float4 b = *(const float4*)(src + i * 8 + 4);
    uint4 u;
    u.x = pack2bf(a.x, a.y); u.y = pack2bf(a.z, a.w);
    u.z = pack2bf(b.x, b.y); u.w = pack2bf(b.z, b.w);
    const size_t fb = (((size_t)(mh * 8 + kc)) * 8 + mt) * 512 + (hi * 16 + lo) * 8;
    *(uint4*)(void*)(out + (size_t)sel * 65536 + fb) = u;
}

// ---- FUSED transpose + Q/K/V conv, SEL-LOOP version. Grid (72, 2, 8).
// Block (n-tile-pair, mh, b): transpose src once -> Q conv; transpose tgt
// once -> K conv -> V conv. Each transpose amortized over the sel loop;
// tgt tile shared by K and V. conv core / epilogues identical to verified R26.
__global__ __launch_bounds__(256, 3) void conv_qkv_kernel(
    const float* __restrict__ srcf, const float* __restrict__ tgtf,
    const bf16* __restrict__ Wbf,
    const float* __restrict__ qb, const float* __restrict__ kb2,
    const float* __restrict__ vb2,
    bf16* __restrict__ Qt, bf16* __restrict__ Kt, bf16* __restrict__ Vt)
{
    __shared__ __align__(16) unsigned char smem[50176];
    float (*tile)[33] = reinterpret_cast<float(*)[33]>(smem);          // 33792 B
    bf16* fx = reinterpret_cast<bf16*>(smem + 33792);                  // 16384 B
    float (*red)[36] = reinterpret_cast<float(*)[36]>(smem);           // aliases tile

    const int b  = blockIdx.z;
    const int mh = blockIdx.y;
    const int n0 = blockIdx.x * 32;
    const int t  = threadIdx.x;
    const int w  = t >> 6, l = t & 63;
    const int wn = w & 1, wk = w >> 1;
    const int lo = l & 15, hi = l >> 4;

    // phase-1 helper: f32 (c,n) tile load, 8 threads/row x float4
    auto load_tile = [&](const float* __restrict__ Xf) {
        const int trow = t >> 3, tf = t & 7;
#pragma unroll
        for (int p = 0; p < 8; ++p) {
            const int c = trow + p * 32;
            float4 v = *(const float4*)(Xf + ((size_t)b * DIM + c) * NPIX + n0 + tf * 4);
            tile[c][tf * 4 + 0] = v.x; tile[c][tf * 4 + 1] = v.y;
            tile[c][tf * 4 + 2] = v.z; tile[c][tf * 4 + 3] = v.w;
        }
    };
    // phase-2 helper: pack fragment-order bf16: fx[wn][kc][hi*16+lo][j]
    auto pack_tile = [&]() {
        const int pwn = t >> 7, r = t & 127;
        const int pkc = r >> 4, phi = (r >> 2) & 3, plo0 = (r & 3) * 4;
#pragma unroll
        for (int lo2 = 0; lo2 < 4; ++lo2) {
            const int plo = plo0 + lo2;
            const int row = pkc * 32 + phi * 8;
            const int col = pwn * 16 + plo;
            uint4 u;
            u.x = pack2bf(tile[row + 0][col], tile[row + 1][col]);
            u.y = pack2bf(tile[row + 2][col], tile[row + 3][col]);
            u.z = pack2bf(tile[row + 4][col], tile[row + 5][col]);
            u.w = pack2bf(tile[row + 6][col], tile[row + 7][col]);
            *(uint4*)(void*)&fx[(size_t)pwn * 4096 + pkc * 512 + (phi * 16 + plo) * 8] = u;
        }
    };
    // phase-3 helper: verified conv core + K-reduction + epilogue for one sel
    auto do_conv = [&](int sel) {
        const float* bias = sel == 0 ? qb : sel == 1 ? kb2 : vb2;
        const float scale = sel == 0 ? SCALE_L2E : 1.0f;
        bf16* Yb = sel == 0 ? Qt : sel == 1 ? Kt : Vt;
        const bf16* fxw = fx + (size_t)wn * 4096;
        const bf16* wp  = Wbf + (size_t)sel * 65536 + (size_t)mh * 32768 + l * 8;

        f32x4 acc[8];
#pragma unroll
        for (int mt = 0; mt < 8; ++mt) acc[mt] = (f32x4){0.f, 0.f, 0.f, 0.f};

        const int kbase = wk * 4;
        bf16x8 a = *(const bf16x8*)(const void*)(fxw + kbase * 512 + l * 8);
        bf16x8 bfr[8];
#pragma unroll
        for (int mt = 0; mt < 8; ++mt)
            bfr[mt] = *(const bf16x8*)(const void*)(wp + (size_t)(kbase * 8 + mt) * 512);

#pragma unroll
        for (int ki = 0; ki < 4; ++ki) {
            const int kn = kbase + ((ki + 1) & 3);   // wrap: harmless reload
            bf16x8 a2 = *(const bf16x8*)(const void*)(fxw + kn * 512 + l * 8);
            bf16x8 bfr2[8];
#pragma unroll
            for (int mt = 0; mt < 8; ++mt)
                bfr2[mt] = *(const bf16x8*)(const void*)(wp + (size_t)(kn * 8 + mt) * 512);
#pragma unroll
            for (int mt = 0; mt < 8; ++mt)
                acc[mt] = __builtin_amdgcn_mfma_f32_16x16x32_bf16(a, bfr[mt], acc[mt], 0, 0, 0);
            a = a2;
#pragma unroll
            for (int mt = 0; mt < 8; ++mt) bfr[mt] = bfr2[mt];
        }

        if (wk == 1) {
#pragma unroll
            for (int mt = 0; mt < 8; ++mt)
                *(float4*)&red[wn * 64 + l][mt * 4] = make_float4(acc[mt][0], acc[mt][1],
                                                                  acc[mt][2], acc[mt][3]);
        }
        __syncthreads();
        if (wk == 0) {
#pragma unroll
            for (int mt = 0; mt < 8; ++mt) {
                float4 v = *(float4*)&red[wn * 64 + l][mt * 4];
                acc[mt][0] += v.x; acc[mt][1] += v.y; acc[mt][2] += v.z; acc[mt][3] += v.w;
            }

            const int nb = n0 + wn * 16 + hi * 4;
#pragma unroll
            for (int mt = 0; mt < 8; ++mt) {
                const int m = mh * 128 + mt * 16 + lo;
                const float bv = bias[m];
                if (sel < 2) {   // QF/KF fragment-order, scaled
                    const int h = m >> 6, d = m & 63;
                    const size_t fb = (((size_t)(b * NHEADS + h) * KCN + (nb >> 5)) * 4 + (d >> 4)) * 512
                                    + ((((d >> 3) & 1) * 32) + (nb & 31)) * 8 + (d & 7);
#pragma unroll
                    for (int r = 0; r < 4; ++r)
                        Yb[fb + r * 8] = __float2bfloat16((acc[mt][r] + bv) * scale);
                } else {         // VF fragment-order
                    const int h = m >> 6, dv = m & 63;
                    const size_t fb = ((((size_t)(b * NHEADS + h) * KCN + (nb >> 5)) * 2 + ((nb >> 4) & 1)) * 2
                                       + (dv >> 5)) * 512
                                    + ((((nb >> 3) & 1) * 32) + (dv & 31)) * 8 + (nb & 7);
                    uint2 u = make_uint2(pack2bf(acc[mt][0] + bv, acc[mt][1] + bv),
                                         pack2bf(acc[mt][2] + bv, acc[mt][3] + bv));
                    *(uint2*)(void*)(Yb + fb) = u;
                }
            }
        }
        __syncthreads();   // red (aliasing tile) consumed before reuse/overwrite
    };

    // src -> Q
    load_tile(srcf);
    __syncthreads();
    pack_tile();
    __syncthreads();
    do_conv(0);
    // tgt -> K, V (tile/red alias safe: red(Q) consumed at do_conv(0) tail barrier)
    load_tile(tgtf);
    __syncthreads();
    pack_tile();
    __syncthreads();
    do_conv(1);
    do_conv(2);
}

// ---- final conv: Op (fragment-order) x W3 -> f32 (b,c,n) out.
__global__ __launch_bounds__(256, 3) void conv_out_kernel(
    const bf16* __restrict__ X, const bf16* __restrict__ Wb,
    const float* __restrict__ bias, float* __restrict__ Yf)
{
    const int b  = blockIdx.z, mh = blockIdx.y;
    const int n0 = blockIdx.x * 32;
    const int w  = threadIdx.x >> 6, l = threadIdx.x & 63;
    const int wn = w & 1, wk = w >> 1;
    const int lo = l & 15, hi = l >> 4;

    __shared__ float red[2][64][36];

    const int ntile = blockIdx.x * 2 + wn;
    const bf16* xp = X + ((size_t)(b * NTN + ntile) * 8) * 512 + l * 8;
    const bf16* wp = Wb + (size_t)mh * 32768 + l * 8;

    f32x4 acc[8];
#pragma unroll
    for (int mt = 0; mt < 8; ++mt) acc[mt] = (f32x4){0.f, 0.f, 0.f, 0.f};

    const int kbase = wk * 4;
    bf16x8 a = *(const bf16x8*)(const void*)(xp + (size_t)kbase * 512);
    bf16x8 bfr[8];
#pragma unroll
    for (int mt = 0; mt < 8; ++mt)
        bfr[mt] = *(const bf16x8*)(const void*)(wp + (size_t)(kbase * 8 + mt) * 512);

#pragma unroll
    for (int ki = 0; ki < 4; ++ki) {
        const int kn = kbase + ((ki + 1) & 3);
        bf16x8 a2 = *(const bf16x8*)(const void*)(xp + (size_t)kn * 512);
        bf16x8 bfr2[8];
#pragma unroll
        for (int mt = 0; mt < 8; ++mt)
            bfr2[mt] = *(const bf16x8*)(const void*)(wp + (size_t)(kn * 8 + mt) * 512);
#pragma unroll
        for (int mt = 0; mt < 8; ++mt)
            acc[mt] = __builtin_amdgcn_mfma_f32_16x16x32_bf16(a, bfr[mt], acc[mt], 0, 0, 0);
        a = a2;
#pragma unroll
        for (int mt = 0; mt < 8; ++mt) bfr[mt] = bfr2[mt];
    }

    if (wk == 1) {
#pragma unroll
        for (int mt = 0; mt < 8; ++mt)
            *(float4*)&red[wn][l][mt * 4] = make_float4(acc[mt][0], acc[mt][1],
                                                        acc[mt][2], acc[mt][3]);
    }
    __syncthreads();
    if (wk != 0) return;

#pragma unroll
    for (int mt = 0; mt < 8; ++mt) {
        float4 v = *(float4*)&red[wn][l][mt * 4];
        acc[mt][0] += v.x; acc[mt][1] += v.y; acc[mt][2] += v.z; acc[mt][3] += v.w;
    }

    const int nb = n0 + wn * 16 + hi * 4;
#pragma unroll
    for (int mt = 0; mt < 8; ++mt) {
        const int m = mh * 128 + mt * 16 + lo;
        const float bv = bias[m];
        float4 v = make_float4(acc[mt][0] + bv, acc[mt][1] + bv,
                               acc[mt][2] + bv, acc[mt][3] + bv);
        *(float4*)(void*)(Yf + ((size_t)b * DIM + m) * NPIX + nb) = v;
    }
}

// ---- MFMA flash attention (R24, verified): 128-q blocks, 4 waves (wq, wk):
// wq owns 64 q (2 subtiles qs); wk owns 36 chunks kc = wk + 2i. Depth-1
// ping-pong; fragment-order operands; 2-way reduction per (wq, qs).
// Grid (18,4,8), block 256.
__global__ __launch_bounds__(256, 2) void attn_kernel(
    const bf16* __restrict__ Qt, const bf16* __restrict__ Kt,
    const bf16* __restrict__ Vt, bf16* __restrict__ Op)
{
    const int b = blockIdx.z, h = blockIdx.y;
    const int w = threadIdx.x >> 6;
    const int wq = w & 1, wk = w >> 1;
    const int l = threadIdx.x & 63;
    const int ln = l & 31, h2 = l >> 5;
    const int bh = b * NHEADS + h;
    const int qt = blockIdx.x;

    __shared__ float red[2][2][32][68];   // [wq][qs][q][d]
    __shared__ float lred[2][2][32];      // [wq][qs][q]

    const bf16* QB = Qt + ((size_t)bh * KCN + qt * 4 + wq * 2) * 2048 + l * 8;
    const bf16* KB = Kt + (size_t)bh * KCN * 2048 + l * 8;
    const bf16* VB = Vt + (size_t)bh * KCN * 2048 + l * 8;

    bf16x8 qf[2][4];
#pragma unroll
    for (int qs = 0; qs < 2; ++qs)
#pragma unroll
        for (int dk = 0; dk < 4; ++dk)
            qf[qs][dk] = *(const bf16x8*)(const void*)(QB + qs * 2048 + dk * 512);

    f32x16 oacc[2][2];
#pragma unroll
    for (int qs = 0; qs < 2; ++qs)
#pragma unroll
        for (int dt = 0; dt < 2; ++dt)
#pragma unroll
            for (int r = 0; r < 16; ++r) oacc[qs][dt][r] = 0.f;
    float lsum[2] = {0.f, 0.f};

    bf16x8 kfA[4], kfB[4];
    bf16x8 vfA[2][2], vfB[2][2];

    auto load_chunk = [&](int kc_, bf16x8 (&kfD)[4], bf16x8 (&vfD)[2][2]) {
        const bf16* KBn = KB + (size_t)kc_ * 2048;
        const bf16* VBn = VB + (size_t)kc_ * 2048;
#pragma unroll
        for (int dk = 0; dk < 4; ++dk)
            kfD[dk] = *(const bf16x8*)(const void*)(KBn + dk * 512);
#pragma unroll
        for (int kb = 0; kb < 2; ++kb)
#pragma unroll
            for (int dt = 0; dt < 2; ++dt)
                vfD[kb][dt] = *(const bf16x8*)(const void*)(VBn + kb * 1024 + dt * 512);
    };

    auto compute = [&](const bf16x8 (&kfX)[4], const bf16x8 (&vfX)[2][2]) {
#pragma unroll
        for (int qs = 0; qs < 2; ++qs) {
            f32x16 s;
#pragma unroll
            for (int r = 0; r < 16; ++r) s[r] = 0.f;
#pragma unroll
            for (int dk = 0; dk < 4; ++dk)
                s = __builtin_amdgcn_mfma_f32_32x32x16_bf16(kfX[dk], qf[qs][dk], s, 0, 0, 0);

            float ls = 0.f;
            unsigned int pk[8];
#pragma unroll
            for (int p = 0; p < 8; ++p) {
                float ea = __builtin_amdgcn_exp2f(
                    __builtin_amdgcn_fmed3f(s[2 * p],     -CLAMP_L2E, CLAMP_L2E));
                float eb = __builtin_amdgcn_exp2f(
                    __builtin_amdgcn_fmed3f(s[2 * p + 1], -CLAMP_L2E, CLAMP_L2E));
                ls += ea + eb;
                pk[p] = pack2bf(ea, eb);
            }
            lsum[qs] += ls;

            unsigned int c00 = pk[0], c02 = pk[2], c01 = pk[1], c03 = pk[3];
            unsigned int c10 = pk[4], c12 = pk[6], c11 = pk[5], c13 = pk[7];
            asm("v_permlane32_swap_b32 %0, %1" : "+v"(c00), "+v"(c02));
            asm("v_permlane32_swap_b32 %0, %1" : "+v"(c01), "+v"(c03));
            asm("v_permlane32_swap_b32 %0, %1" : "+v"(c10), "+v"(c12));
            asm("v_permlane32_swap_b32 %0, %1" : "+v"(c11), "+v"(c13));
            union { unsigned int u[4]; bf16x8 v; } pb0, pb1;
            pb0.u[0] = c00; pb0.u[1] = c01; pb0.u[2] = c02; pb0.u[3] = c03;
            pb1.u[0] = c10; pb1.u[1] = c11; pb1.u[2] = c12; pb1.u[3] = c13;

#pragma unroll
            for (int dt = 0; dt < 2; ++dt) {
                oacc[qs][dt] = __builtin_amdgcn_mfma_f32_32x32x16_bf16(vfX[0][dt], pb0.v, oacc[qs][dt], 0, 0, 0);
                oacc[qs][dt] = __builtin_amdgcn_mfma_f32_32x32x16_bf16(vfX[1][dt], pb1.v, oacc[qs][dt], 0, 0, 0);
            }
        }
    };

    load_chunk(wk, kfA, vfA);
    for (int i = 0; i < 36; i += 2) {
        load_chunk(wk + 2 * (i + 1), kfB, vfB);
        compute(kfA, vfA);
        load_chunk(i + 2 < 36 ? wk + 2 * (i + 2) : wk, kfA, vfA);
        compute(kfB, vfB);
    }

#pragma unroll
    for (int qs = 0; qs < 2; ++qs) lsum[qs] += __shfl_xor(lsum[qs], 32);
    if (wk == 1) {
        if (h2 == 0) { lred[wq][0][ln] = lsum[0]; lred[wq][1][ln] = lsum[1]; }
#pragma unroll
        for (int qs = 0; qs < 2; ++qs)
#pragma unroll
            for (int dt = 0; dt < 2; ++dt)
#pragma unroll
                for (int g = 0; g < 4; ++g) {
                    float4 v = make_float4(oacc[qs][dt][g * 4 + 0], oacc[qs][dt][g * 4 + 1],
                                           oacc[qs][dt][g * 4 + 2], oacc[qs][dt][g * 4 + 3]);
                    *(float4*)&red[wq][qs][ln][dt * 32 + g * 8 + h2 * 4] = v;
                }
    }
    __syncthreads();

    if (wk == 0) {
#pragma unroll
        for (int qs = 0; qs < 2; ++qs) {
#pragma unroll
            for (int dt = 0; dt < 2; ++dt)
#pragma unroll
                for (int g = 0; g < 4; ++g) {
                    float4 v = *(float4*)&red[wq][qs][ln][dt * 32 + g * 8 + h2 * 4];
                    oacc[qs][dt][g * 4 + 0] += v.x; oacc[qs][dt][g * 4 + 1] += v.y;
                    oacc[qs][dt][g * 4 + 2] += v.z; oacc[qs][dt][g * 4 + 3] += v.w;
                }
            const float inv = 1.f / (lsum[qs] + lred[wq][qs][ln]);

            const int ntile = qt * 8 + wq * 4 + qs * 2 + (ln >> 4);
            bf16* opb = Op + (((size_t)(b * NTN + ntile)) * 8 + h * 2) * 512
                      + (ln & 15) * 8 + h2 * 4;
#pragma unroll
            for (int dt = 0; dt < 2; ++dt)
#pragma unroll
                for (int g = 0; g < 4; ++g) {
                    float v0 = oacc[qs][dt][g * 4 + 0] * inv;
                    float v1 = oacc[qs][dt][g * 4 + 1] * inv;
                    float v2 = oacc[qs][dt][g * 4 + 2] * inv;
                    float v3 = oacc[qs][dt][g * 4 + 3] * inv;
                    uint2 u = make_uint2(pack2bf(v0, v1), pack2bf(v2, v3));
                    *(uint2*)(void*)(opb + (size_t)dt * 512 + g * 128) = u;
                }
        }
    }
}

extern "C" void kernel_launch(void* const* d_in, const int* in_sizes, int n_in,
                              void* d_out, int out_size, void* d_ws, size_t ws_size,
                              hipStream_t stream) {
    const float* src = (const float*)d_in[0];
    const float* tgt = (const float*)d_in[1];
    const float* qw  = (const float*)d_in[2];
    const float* qb  = (const float*)d_in[3];
    const float* kw  = (const float*)d_in[4];
    const float* kb  = (const float*)d_in[5];
    const float* vw  = (const float*)d_in[6];
    const float* vb  = (const float*)d_in[7];
    const float* ow  = (const float*)d_in[8];
    const float* ob  = (const float*)d_in[9];
    float* out = (float*)d_out;

    const size_t TEN = (size_t)NBATCH * DIM * NPIX;  // 4,718,592
    bf16* Wbf  = (bf16*)d_ws;          // 4 x 65536, fragment-order
    bf16* Qt   = Wbf + 4 * 65536;      // fragment-order QF, prescaled
    bf16* Kt   = Qt  + TEN;            // fragment-order KF
    bf16* Vt   = Kt  + TEN;            // fragment-order VF
    bf16* Op   = Vt  + TEN;            // fragment-order FOp

    cvt_w_kernel<<<dim3(32, 4, 1), 256, 0, stream>>>(qw, kw, vw, ow, Wbf);

    conv_qkv_kernel<<<dim3(NPIX / 32, 2, NBATCH), 256, 0, stream>>>(
        src, tgt, Wbf, qb, kb, vb, Qt, Kt, Vt);

    attn_kernel<<<dim3(NPIX / 128, NHEADS, NBATCH), 256, 0, stream>>>(Qt, Kt, Vt, Op);

    conv_out_kernel<<<dim3(NPIX / 32, 2, NBATCH), 256, 0, stream>>>(
        Op, Wbf + 3 * 65536, ob, out);
}